// Round 12
// baseline (3748.231 us; speedup 1.0000x reference)
//
#include <hip/hip_runtime.h>
#include <hip/hip_bf16.h>

// N=200000, E=3200000, R=8, B=2, IN=128, H=32, OUT=128, U=10000, T=50000.

typedef float f4 __attribute__((ext_vector_type(4)));
typedef short s8 __attribute__((ext_vector_type(8)));   // 8 bf16 = 4 VGPRs (MFMA frag)
typedef unsigned short u16;
typedef u16 us4 __attribute__((ext_vector_type(4)));   // 4 bf16 = 8 bytes

__device__ inline u16 f2b(float f) {
    __hip_bfloat16 h = __float2bfloat16(f);
    return __builtin_bit_cast(u16, h);
}
__device__ inline float b2f(u16 s) {
    return __bfloat162float(__builtin_bit_cast(__hip_bfloat16, s));
}
__device__ inline f4 b4f(us4 v) {
    f4 r = {b2f(v.x), b2f(v.y), b2f(v.z), b2f(v.w)};
    return r;
}
__device__ inline float blo(unsigned v) { return b2f((u16)(v & 0xffffu)); }
__device__ inline float bhi(unsigned v) { return b2f((u16)(v >> 16)); }
__device__ inline unsigned bpack(float a, float b) {
    return (unsigned)f2b(a) | ((unsigned)f2b(b) << 16);
}

#define NBLK 256      // scatter blocks
#define MAXB 800      // >= NB = ceil(N/256) = 782
#define PADK 136      // 128 + 8 bf16 pad (k_hb LDS)
#define ST0 34        // pull0 LDS acc stride (pad avoids cross-stream bank clash)
#define STU 66        // pull_u LDS acc stride

// ---------------------------------------------------------------------------
// Layer-0 basis+selfloop GEMM on MFMA (unchanged from round 11).
__global__ __launch_bounds__(256, 3)
void k_hb(const float* __restrict__ x, const float* __restrict__ V,
          const float* __restrict__ loopw, const float* __restrict__ bias,
          u16* __restrict__ hb, u16* __restrict__ agg, int nNodes)
{
    __shared__ u16 XA[64 * PADK];
    __shared__ u16 WB[96 * PADK];
    __shared__ float sbias[32];

    const int t = threadIdx.x;
    const int base = blockIdx.x * 64;

    if (t < 32) sbias[t] = bias[t];
    for (int i = t; i < 3072; i += 256) {
        if (i < 2048) {
            f4 v = *(const f4*)(V + (long)i * 4);
            int b = i >> 10, k = (i >> 3) & 127, o0 = (i & 7) * 4;
            int col = b * 32 + o0;
            #pragma unroll
            for (int s = 0; s < 4; ++s) WB[(col + s) * PADK + k] = f2b(v[s]);
        } else {
            int j = i - 2048;
            f4 v = *(const f4*)(loopw + (long)j * 4);
            int k = j >> 3, o0 = (j & 7) * 4;
            int col = 64 + o0;
            #pragma unroll
            for (int s = 0; s < 4; ++s) WB[(col + s) * PADK + k] = f2b(v[s]);
        }
    }
    for (int i = t; i < 2048; i += 256) {
        int row = i >> 5, c4 = i & 31;
        long gr = (long)min(base + row, nNodes - 1);
        f4 xv = *(const f4*)(x + gr * 128 + (long)c4 * 4);
        us4 v = {f2b(xv[0]), f2b(xv[1]), f2b(xv[2]), f2b(xv[3])};
        *(us4*)&XA[row * PADK + c4 * 4] = v;
    }
    __syncthreads();

    const int w    = t >> 6;
    const int l    = t & 63;
    const int rsel = l & 15;
    const int kg   = l >> 4;

    f4 acc[6] = {};
    for (int ks = 0; ks < 4; ++ks) {
        s8 a = *(const s8*)&XA[(w * 16 + rsel) * PADK + ks * 32 + kg * 8];
        #pragma unroll
        for (int ct = 0; ct < 6; ++ct) {
            s8 b = *(const s8*)&WB[(ct * 16 + rsel) * PADK + ks * 32 + kg * 8];
            acc[ct] = __builtin_amdgcn_mfma_f32_16x16x32_bf16(a, b, acc[ct], 0, 0, 0);
        }
    }

    #pragma unroll
    for (int ct = 0; ct < 6; ++ct) {
        int col = ct * 16 + rsel;
        #pragma unroll
        for (int r = 0; r < 4; ++r) {
            int node = base + w * 16 + kg * 4 + r;
            if (node < nNodes) {
                float v = acc[ct][r];
                if (col < 64) hb[(long)node * 64 + col] = f2b(v);
                else          agg[(long)node * 32 + (col - 64)] = f2b(v + sbias[col - 64]);
            }
        }
    }
}

// ---------------------------------------------------------------------------
// Bucketed edge partition (histogram/scan/scatter; final-order pass removed).
__global__ __launch_bounds__(256)
void k_bhist2(const int* __restrict__ dst, int* __restrict__ hist,
              int nEdges, int nB, int chunk)
{
    __shared__ int hloc[MAXB];
    for (int i = threadIdx.x; i < nB; i += 256) hloc[i] = 0;
    __syncthreads();
    const int ebeg = blockIdx.x * chunk;
    const int eend = min(ebeg + chunk, nEdges);
    for (int e = ebeg + threadIdx.x; e < eend; e += 256)
        atomicAdd(&hloc[dst[e] >> 8], 1);
    __syncthreads();
    for (int i = threadIdx.x; i < nB; i += 256)
        hist[blockIdx.x * MAXB + i] = hloc[i];
}

__global__ __launch_bounds__(256)
void k_colscan(const int* __restrict__ hist, int* __restrict__ base,
               int* __restrict__ colsum, int nB)
{
    __shared__ int s[256];
    const int b = blockIdx.x;
    const int t = threadIdx.x;
    int v = hist[t * MAXB + b];
    s[t] = v; __syncthreads();
    for (int off = 1; off < 256; off <<= 1) {
        int tmp = (t >= off) ? s[t - off] : 0;
        __syncthreads();
        s[t] += tmp;
        __syncthreads();
    }
    base[t * MAXB + b] = s[t] - v;
    if (t == 255) colsum[b] = s[255];
}

__global__ __launch_bounds__(1024)
void k_bscan2(const int* __restrict__ colsum, int* __restrict__ bb,
              int nB, int nEdges)
{
    __shared__ int s[1024];
    int t = threadIdx.x;
    int v = (t < nB) ? colsum[t] : 0;
    s[t] = v; __syncthreads();
    for (int off = 1; off < 1024; off <<= 1) {
        int tmp = (t >= off) ? s[t - off] : 0;
        __syncthreads();
        s[t] += tmp;
        __syncthreads();
    }
    if (t < nB) bb[t] = s[t] - v;
    if (t == 0) bb[nB] = nEdges;
}

__global__ __launch_bounds__(256)
void k_bscatter2(const int* __restrict__ src, const int* __restrict__ dst,
                 const int* __restrict__ et, const int* __restrict__ base,
                 const int* __restrict__ bb, unsigned* __restrict__ bpk,
                 int nEdges, int nB, int chunk)
{
    __shared__ int sbase[MAXB];
    __shared__ int cur[MAXB];
    for (int i = threadIdx.x; i < nB; i += 256) {
        sbase[i] = bb[i] + base[blockIdx.x * MAXB + i];
        cur[i] = 0;
    }
    __syncthreads();
    const int ebeg = blockIdx.x * chunk;
    const int eend = min(ebeg + chunk, nEdges);
    for (int e = ebeg + threadIdx.x; e < eend; e += 256) {
        int d = dst[e];
        int b = d >> 8;
        int r = atomicAdd(&cur[b], 1);
        bpk[sbase[b] + r] = ((unsigned)(d & 255) << 21)
                          | ((unsigned)src[e] << 3) | (unsigned)et[e];
    }
}

// ---------------------------------------------------------------------------
// Referenced-node set: flags + compaction.
__global__ __launch_bounds__(256)
void k_zerof(int* __restrict__ flags4, int n4, int* __restrict__ cnt)
{
    int i = blockIdx.x * 256 + threadIdx.x;
    if (i < n4) flags4[i] = 0;
    if (i == 0) *cnt = 0;
}

__global__ __launch_bounds__(256)
void k_flags(const int* __restrict__ ui, const int* __restrict__ ii,
             const int* __restrict__ tes, const int* __restrict__ ted,
             int U, int T, unsigned char* __restrict__ flags)
{
    int g = blockIdx.x * 256 + threadIdx.x;
    int idx;
    if (g < U)               idx = ui[g];
    else if (g < 2 * U)      idx = ii[g - U];
    else if (g < 2 * U + T)  idx = tes[g - 2 * U];
    else if (g < 2 * U + 2 * T) idx = ted[g - 2 * U - T];
    else return;
    flags[idx] = 1;
}

__global__ __launch_bounds__(256)
void k_compact(const unsigned char* __restrict__ flags, int* __restrict__ list,
               int* __restrict__ cnt, int n)
{
    __shared__ int s[256];
    __shared__ int bofs;
    int t = threadIdx.x;
    int i = blockIdx.x * 256 + t;
    int f = (i < n) ? (int)flags[i] : 0;
    s[t] = f; __syncthreads();
    for (int off = 1; off < 256; off <<= 1) {
        int v = (t >= off) ? s[t - off] : 0;
        __syncthreads();
        s[t] += v;
        __syncthreads();
    }
    if (t == 255) bofs = atomicAdd(cnt, s[255]);
    __syncthreads();
    if (f) list[bofs + s[t] - 1] = i;
}

// ---------------------------------------------------------------------------
// Layer-0 push-per-bucket: block b owns nodes [b*256, b*256+256) with
// acc[256][ST0] f32 in LDS. 8 streams of 32 lanes walk the bucket's edge
// list (any order); per edge one 128B hb-row gather; basis partials folded
// by shfl_xor(16); LDS atomicAdd into the dst node's accumulator.
__global__ __launch_bounds__(256)
void k_pull0(const int* __restrict__ bb, const unsigned* __restrict__ bpk,
             const float* __restrict__ comb, const u16* __restrict__ hb,
             u16* __restrict__ h0, int nNodes)
{
    __shared__ float sacc[256 * ST0];
    __shared__ float sc[16];
    const int t = threadIdx.x;
    const int b = blockIdx.x;
    if (t < 16) sc[t] = comb[t];
    const int nb0 = b * 256;
    for (int i = t; i < 4096; i += 256) {          // init = selfloop (h0)
        int d = i >> 4, o2 = i & 15;
        int n = nb0 + d;
        if (n < nNodes) {
            unsigned v = *(const unsigned*)(h0 + (long)n * 32 + 2 * o2);
            sacc[d * ST0 + 2 * o2]     = blo(v);
            sacc[d * ST0 + 2 * o2 + 1] = bhi(v);
        }
    }
    __syncthreads();

    const int stream = t >> 5;          // 0..7
    const int l      = t & 31;
    const int sub    = l >> 4;          // basis index
    const int i2     = l & 15;
    const long goff  = (long)sub * 32 + 2 * i2;
    const int ebeg = bb[b], eend = bb[b + 1];

    int j = ebeg + stream;
    for (; j + 24 < eend; j += 32) {
        unsigned p0 = bpk[j], p1 = bpk[j + 8], p2 = bpk[j + 16], p3 = bpk[j + 24];
        unsigned v0 = *(const unsigned*)(hb + (long)((p0 >> 3) & 0x3FFFFu) * 64 + goff);
        unsigned v1 = *(const unsigned*)(hb + (long)((p1 >> 3) & 0x3FFFFu) * 64 + goff);
        unsigned v2 = *(const unsigned*)(hb + (long)((p2 >> 3) & 0x3FFFFu) * 64 + goff);
        unsigned v3 = *(const unsigned*)(hb + (long)((p3 >> 3) & 0x3FFFFu) * 64 + goff);
        float c0 = sc[(p0 & 7) * 2 + sub];
        float c1 = sc[(p1 & 7) * 2 + sub];
        float c2 = sc[(p2 & 7) * 2 + sub];
        float c3 = sc[(p3 & 7) * 2 + sub];
        float lo0 = c0 * blo(v0), hi0 = c0 * bhi(v0);
        float lo1 = c1 * blo(v1), hi1 = c1 * bhi(v1);
        float lo2 = c2 * blo(v2), hi2 = c2 * bhi(v2);
        float lo3 = c3 * blo(v3), hi3 = c3 * bhi(v3);
        lo0 += __shfl_xor(lo0, 16);  hi0 += __shfl_xor(hi0, 16);
        lo1 += __shfl_xor(lo1, 16);  hi1 += __shfl_xor(hi1, 16);
        lo2 += __shfl_xor(lo2, 16);  hi2 += __shfl_xor(hi2, 16);
        lo3 += __shfl_xor(lo3, 16);  hi3 += __shfl_xor(hi3, 16);
        if (sub == 0) {
            int a0 = (int)(p0 >> 21) * ST0 + 2 * i2;
            int a1 = (int)(p1 >> 21) * ST0 + 2 * i2;
            int a2 = (int)(p2 >> 21) * ST0 + 2 * i2;
            int a3 = (int)(p3 >> 21) * ST0 + 2 * i2;
            atomicAdd(&sacc[a0], lo0);  atomicAdd(&sacc[a0 + 1], hi0);
            atomicAdd(&sacc[a1], lo1);  atomicAdd(&sacc[a1 + 1], hi1);
            atomicAdd(&sacc[a2], lo2);  atomicAdd(&sacc[a2 + 1], hi2);
            atomicAdd(&sacc[a3], lo3);  atomicAdd(&sacc[a3 + 1], hi3);
        }
    }
    for (; j < eend; j += 8) {
        unsigned p0 = bpk[j];
        unsigned v0 = *(const unsigned*)(hb + (long)((p0 >> 3) & 0x3FFFFu) * 64 + goff);
        float c0 = sc[(p0 & 7) * 2 + sub];
        float lo0 = c0 * blo(v0), hi0 = c0 * bhi(v0);
        lo0 += __shfl_xor(lo0, 16);  hi0 += __shfl_xor(hi0, 16);
        if (sub == 0) {
            int a0 = (int)(p0 >> 21) * ST0 + 2 * i2;
            atomicAdd(&sacc[a0], lo0);  atomicAdd(&sacc[a0 + 1], hi0);
        }
    }
    __syncthreads();

    for (int i = t; i < 4096; i += 256) {          // tanh + writeback
        int d = i >> 4, o2 = i & 15;
        int n = nb0 + d;
        if (n < nNodes) {
            float a = sacc[d * ST0 + 2 * o2];
            float c = sacc[d * ST0 + 2 * o2 + 1];
            *(unsigned*)(h0 + (long)n * 32 + 2 * o2) = bpack(tanhf(a), tanhf(c));
        }
    }
}

// ---------------------------------------------------------------------------
// Layers 1/2 push-per-bucket in INPUT space: acc[256][STU] f32 (basis 0 at
// cols 0..31, basis 1 at 32..63). 16 streams of 16 lanes; per edge one 64B
// gather; 4 LDS atomicAdds per lane.
__global__ __launch_bounds__(256)
void k_pull_u(const int* __restrict__ bb, const unsigned* __restrict__ bpk,
              const float* __restrict__ comb, const u16* __restrict__ hsrc,
              u16* __restrict__ u, int nNodes)
{
    __shared__ float sacc[256 * STU];
    __shared__ float sc[16];
    const int t = threadIdx.x;
    const int b = blockIdx.x;
    if (t < 16) sc[t] = comb[t];
    for (int i = t; i < 256 * STU; i += 256) sacc[i] = 0.f;
    __syncthreads();

    const int stream = t >> 4;          // 0..15
    const int i2     = t & 15;
    const int ebeg = bb[b], eend = bb[b + 1];

    int j = ebeg + stream;
    for (; j + 32 < eend; j += 48) {
        unsigned p0 = bpk[j], p1 = bpk[j + 16], p2 = bpk[j + 32];
        unsigned v0 = *(const unsigned*)(hsrc + (long)((p0 >> 3) & 0x3FFFFu) * 32 + 2 * i2);
        unsigned v1 = *(const unsigned*)(hsrc + (long)((p1 >> 3) & 0x3FFFFu) * 32 + 2 * i2);
        unsigned v2 = *(const unsigned*)(hsrc + (long)((p2 >> 3) & 0x3FFFFu) * 32 + 2 * i2);
        int r0 = (p0 & 7) * 2, r1 = (p1 & 7) * 2, r2 = (p2 & 7) * 2;
        int a0 = (int)(p0 >> 21) * STU + 2 * i2;
        int a1 = (int)(p1 >> 21) * STU + 2 * i2;
        int a2 = (int)(p2 >> 21) * STU + 2 * i2;
        float l0 = blo(v0), h0v = bhi(v0);
        float l1 = blo(v1), h1v = bhi(v1);
        float l2 = blo(v2), h2v = bhi(v2);
        atomicAdd(&sacc[a0],          sc[r0] * l0);
        atomicAdd(&sacc[a0 + 1],      sc[r0] * h0v);
        atomicAdd(&sacc[a0 + 32],     sc[r0 + 1] * l0);
        atomicAdd(&sacc[a0 + 33],     sc[r0 + 1] * h0v);
        atomicAdd(&sacc[a1],          sc[r1] * l1);
        atomicAdd(&sacc[a1 + 1],      sc[r1] * h1v);
        atomicAdd(&sacc[a1 + 32],     sc[r1 + 1] * l1);
        atomicAdd(&sacc[a1 + 33],     sc[r1 + 1] * h1v);
        atomicAdd(&sacc[a2],          sc[r2] * l2);
        atomicAdd(&sacc[a2 + 1],      sc[r2] * h2v);
        atomicAdd(&sacc[a2 + 32],     sc[r2 + 1] * l2);
        atomicAdd(&sacc[a2 + 33],     sc[r2 + 1] * h2v);
    }
    for (; j < eend; j += 16) {
        unsigned p0 = bpk[j];
        unsigned v0 = *(const unsigned*)(hsrc + (long)((p0 >> 3) & 0x3FFFFu) * 32 + 2 * i2);
        int r0 = (p0 & 7) * 2;
        int a0 = (int)(p0 >> 21) * STU + 2 * i2;
        float l0 = blo(v0), h0v = bhi(v0);
        atomicAdd(&sacc[a0],      sc[r0] * l0);
        atomicAdd(&sacc[a0 + 1],  sc[r0] * h0v);
        atomicAdd(&sacc[a0 + 32], sc[r0 + 1] * l0);
        atomicAdd(&sacc[a0 + 33], sc[r0 + 1] * h0v);
    }
    __syncthreads();

    const int nb0 = b * 256;
    for (int i = t; i < 8192; i += 256) {          // writeback u bf16
        int d = i >> 5, q = i & 31;
        int n = nb0 + d;
        if (n < nNodes) {
            float a = sacc[d * STU + 2 * q];
            float c = sacc[d * STU + 2 * q + 1];
            *(unsigned*)(u + (long)n * 64 + 2 * q) = bpack(a, c);
        }
    }
}

// ---------------------------------------------------------------------------
// Post GEMM for layers 1/2 (unchanged).
__global__ __launch_bounds__(256, 2)
void k_post(const u16* __restrict__ u, const u16* __restrict__ hsrc,
            const float* __restrict__ V, const float* __restrict__ loopw,
            const float* __restrict__ bias, u16* __restrict__ hdst, int nNodes)
{
    __shared__ float CW[96 * 32];
    for (int idx = threadIdx.x; idx < 96 * 32; idx += 256) {
        int i = idx / 32, o = idx % 32;
        CW[idx] = (i < 64) ? V[i * 32 + o]
                           : loopw[(i - 64) * 32 + o];
    }
    __syncthreads();

    const int cg = threadIdx.x & 7;
    const int ng = threadIdx.x >> 3;
    const int c0 = cg * 4;
    const int base = blockIdx.x * 128 + ng * 4;
    if (base >= nNodes) return;

    long rows[4];
    #pragma unroll
    for (int j = 0; j < 4; ++j)
        rows[j] = (long)min(base + j, nNodes - 1);

    float acc[4][4] = {};
    #pragma unroll 2
    for (int i = 0; i < 96; i += 4) {
        f4 w0 = *(const f4*)&CW[(i + 0) * 32 + c0];
        f4 w1 = *(const f4*)&CW[(i + 1) * 32 + c0];
        f4 w2 = *(const f4*)&CW[(i + 2) * 32 + c0];
        f4 w3 = *(const f4*)&CW[(i + 3) * 32 + c0];
        #pragma unroll
        for (int j = 0; j < 4; ++j) {
            f4 hv;
            if (i < 64) hv = b4f(*(const us4*)(u + rows[j] * 64 + i));
            else        hv = b4f(*(const us4*)(hsrc + rows[j] * 32 + (i - 64)));
            #pragma unroll
            for (int q = 0; q < 4; ++q)
                acc[j][q] = fmaf(hv[3], w3[q],
                            fmaf(hv[2], w2[q],
                            fmaf(hv[1], w1[q],
                            fmaf(hv[0], w0[q], acc[j][q]))));
        }
    }

    f4 bv = *(const f4*)(bias + c0);
    #pragma unroll
    for (int j = 0; j < 4; ++j)
        if (base + j < nNodes) {
            us4 v = {f2b(tanhf(acc[j][0] + bv[0])), f2b(tanhf(acc[j][1] + bv[1])),
                     f2b(tanhf(acc[j][2] + bv[2])), f2b(tanhf(acc[j][3] + bv[3]))};
            *(us4*)(hdst + (long)(base + j) * 32 + c0) = v;
        }
}

// ---------------------------------------------------------------------------
// Fused MLP heads + reparameterization over the COMPACTED node list only.
__global__ __launch_bounds__(256, 2)
void k_mlp(const u16* __restrict__ h0, const u16* __restrict__ h1,
           const u16* __restrict__ h2,
           const float* __restrict__ Wm1, const float* __restrict__ bm1,
           const float* __restrict__ Wm2, const float* __restrict__ bm2,
           const float* __restrict__ Ws1, const float* __restrict__ bs1,
           const float* __restrict__ Ws2, const float* __restrict__ bs2,
           const float* __restrict__ noise, float* __restrict__ z,
           const int* __restrict__ list, const int* __restrict__ cnt)
{
    const int count = *cnt;
    const int base = blockIdx.x * 64;
    if (base >= count) return;

    __shared__ float sW1[2][96 * 32];
    __shared__ float sW2[2][32 * 128];
    __shared__ float sb1[2][32];
    __shared__ float sb2[2][128];
    __shared__ float shid[2][64][32];

    for (int i = threadIdx.x; i < 96 * 32; i += 256) { sW1[0][i] = Wm1[i]; sW1[1][i] = Ws1[i]; }
    for (int i = threadIdx.x; i < 32 * 128; i += 256) { sW2[0][i] = Wm2[i]; sW2[1][i] = Ws2[i]; }
    if (threadIdx.x < 32)  { sb1[0][threadIdx.x] = bm1[threadIdx.x]; sb1[1][threadIdx.x] = bs1[threadIdx.x]; }
    if (threadIdx.x < 128) { sb2[0][threadIdx.x] = bm2[threadIdx.x]; sb2[1][threadIdx.x] = bs2[threadIdx.x]; }
    __syncthreads();

    // ---- phase A: hidden = relu(cs @ W1 + b1) ----
    {
        const int head = threadIdx.x >> 7;
        const int rem  = threadIdx.x & 127;
        const int ng   = rem >> 3;
        const int c0   = (rem & 7) * 4;
        const float* sW = sW1[head];
        long rows[4];
        #pragma unroll
        for (int j = 0; j < 4; ++j)
            rows[j] = (long)list[min(base + ng * 4 + j, count - 1)];

        float acc[4][4] = {};
        const u16* hs[3] = {h0, h1, h2};
        #pragma unroll
        for (int part = 0; part < 3; ++part) {
            const u16* hp = hs[part];
            #pragma unroll
            for (int kk = 0; kk < 32; kk += 4) {
                const int k = part * 32 + kk;
                f4 w0 = *(const f4*)&sW[(k + 0) * 32 + c0];
                f4 w1 = *(const f4*)&sW[(k + 1) * 32 + c0];
                f4 w2 = *(const f4*)&sW[(k + 2) * 32 + c0];
                f4 w3 = *(const f4*)&sW[(k + 3) * 32 + c0];
                #pragma unroll
                for (int j = 0; j < 4; ++j) {
                    f4 hv = b4f(*(const us4*)(hp + rows[j] * 32 + kk));
                    #pragma unroll
                    for (int q = 0; q < 4; ++q)
                        acc[j][q] = fmaf(hv[3], w3[q],
                                    fmaf(hv[2], w2[q],
                                    fmaf(hv[1], w1[q],
                                    fmaf(hv[0], w0[q], acc[j][q]))));
                }
            }
        }
        f4 bv = *(const f4*)&sb1[head][c0];
        #pragma unroll
        for (int j = 0; j < 4; ++j) {
            f4 v = {fmaxf(acc[j][0] + bv[0], 0.f), fmaxf(acc[j][1] + bv[1], 0.f),
                    fmaxf(acc[j][2] + bv[2], 0.f), fmaxf(acc[j][3] + bv[3], 0.f)};
            *(f4*)&shid[head][ng * 4 + j][c0] = v;
        }
    }
    __syncthreads();

    // ---- phase B: out = hid @ W2 + b2; z = mean + noise * exp(log_std) ----
    const int ng = threadIdx.x >> 5;
    const int c0 = (threadIdx.x & 31) * 4;
    #pragma unroll
    for (int pass = 0; pass < 2; ++pass) {
        const int nb = pass * 32 + ng * 4;
        float am[4][4] = {}, as_[4][4] = {};
        #pragma unroll 4
        for (int k = 0; k < 32; k += 4) {
            f4 wm0 = *(const f4*)&sW2[0][(k + 0) * 128 + c0];
            f4 wm1 = *(const f4*)&sW2[0][(k + 1) * 128 + c0];
            f4 wm2 = *(const f4*)&sW2[0][(k + 2) * 128 + c0];
            f4 wm3 = *(const f4*)&sW2[0][(k + 3) * 128 + c0];
            f4 ws0 = *(const f4*)&sW2[1][(k + 0) * 128 + c0];
            f4 ws1 = *(const f4*)&sW2[1][(k + 1) * 128 + c0];
            f4 ws2 = *(const f4*)&sW2[1][(k + 2) * 128 + c0];
            f4 ws3 = *(const f4*)&sW2[1][(k + 3) * 128 + c0];
            #pragma unroll
            for (int j = 0; j < 4; ++j) {
                f4 hm = *(const f4*)&shid[0][nb + j][k];
                f4 hv = *(const f4*)&shid[1][nb + j][k];
                #pragma unroll
                for (int q = 0; q < 4; ++q) {
                    am[j][q]  = fmaf(hm[3], wm3[q],
                                fmaf(hm[2], wm2[q],
                                fmaf(hm[1], wm1[q],
                                fmaf(hm[0], wm0[q], am[j][q]))));
                    as_[j][q] = fmaf(hv[3], ws3[q],
                                fmaf(hv[2], ws2[q],
                                fmaf(hv[1], ws1[q],
                                fmaf(hv[0], ws0[q], as_[j][q]))));
                }
            }
        }
        f4 b2m = *(const f4*)&sb2[0][c0];
        f4 b2s = *(const f4*)&sb2[1][c0];
        #pragma unroll
        for (int j = 0; j < 4; ++j) {
            const int idx = base + nb + j;
            if (idx < count) {
                const long n = (long)list[idx];
                f4 nz = *(const f4*)(noise + n * 128 + c0);
                f4 v;
                #pragma unroll
                for (int q = 0; q < 4; ++q)
                    v[q] = fmaf(nz[q], expf(as_[j][q] + b2s[q]), am[j][q] + b2m[q]);
                *(f4*)(z + n * 128 + c0) = v;
            }
        }
    }
}

// ---------------------------------------------------------------------------
__global__ __launch_bounds__(256)
void k_pairs(const float* __restrict__ z, const int* __restrict__ ui,
             const int* __restrict__ ii, float* __restrict__ out, int U, int T)
{
    int w = (blockIdx.x * 256 + threadIdx.x) >> 6;
    int lane = threadIdx.x & 63;
    if (w >= U) return;
    int a = ui[w], b = ii[w];
    float a0 = z[(long)a * 128 + lane], a1 = z[(long)a * 128 + 64 + lane];
    float b0 = z[(long)b * 128 + lane], b1 = z[(long)b * 128 + 64 + lane];
    float* res = out + U + T;
    res[(long)w * 128 + lane] = a0;
    res[(long)w * 128 + 64 + lane] = a1;
    res[(long)(U + w) * 128 + lane] = b0;
    res[(long)(U + w) * 128 + 64 + lane] = b1;
    float d = fmaf(a0, b0, a1 * b1);
    #pragma unroll
    for (int off = 32; off; off >>= 1) d += __shfl_xor(d, off);
    if (lane == 0) out[w] = d;
}

__global__ __launch_bounds__(256)
void k_preds(const float* __restrict__ z, const int* __restrict__ ts,
             const int* __restrict__ td, float* __restrict__ out, int U, int T)
{
    int w = (blockIdx.x * 256 + threadIdx.x) >> 6;
    int lane = threadIdx.x & 63;
    if (w >= T) return;
    int a = ts[w], b = td[w];
    float a0 = z[(long)a * 128 + lane], a1 = z[(long)a * 128 + 64 + lane];
    float b0 = z[(long)b * 128 + lane], b1 = z[(long)b * 128 + 64 + lane];
    float d = fmaf(a0, b0, a1 * b1);
    #pragma unroll
    for (int off = 32; off; off >>= 1) d += __shfl_xor(d, off);
    if (lane == 0) out[U + w] = d;
}

// ---------------------------------------------------------------------------
extern "C" void kernel_launch(void* const* d_in, const int* in_sizes, int n_in,
                              void* d_out, int out_size, void* d_ws, size_t ws_size,
                              hipStream_t stream)
{
    const float* x     = (const float*)d_in[0];
    const int*   src   = (const int*)d_in[1];
    const int*   dst   = (const int*)d_in[2];
    const int*   et    = (const int*)d_in[3];
    const float* noise = (const float*)d_in[4];
    const int*   ui    = (const int*)d_in[5];
    const int*   ii    = (const int*)d_in[6];
    const int*   tes   = (const int*)d_in[7];
    const int*   ted   = (const int*)d_in[8];
    const float* V0    = (const float*)d_in[9];
    const float* comb0 = (const float*)d_in[10];
    const float* loop0 = (const float*)d_in[11];
    const float* b0    = (const float*)d_in[12];
    const float* V1    = (const float*)d_in[13];
    const float* comb1 = (const float*)d_in[14];
    const float* loop1 = (const float*)d_in[15];
    const float* b1    = (const float*)d_in[16];
    const float* V2    = (const float*)d_in[17];
    const float* comb2 = (const float*)d_in[18];
    const float* loop2 = (const float*)d_in[19];
    const float* b2    = (const float*)d_in[20];
    const float* Wm1   = (const float*)d_in[21];
    const float* bm1   = (const float*)d_in[22];
    const float* Wm2   = (const float*)d_in[23];
    const float* bm2   = (const float*)d_in[24];
    const float* Ws1   = (const float*)d_in[25];
    const float* bs1   = (const float*)d_in[26];
    const float* Ws2   = (const float*)d_in[27];
    const float* bs2   = (const float*)d_in[28];

    const int N = in_sizes[0] / 128;   // 200000
    const int E = in_sizes[1];         // 3200000
    const int U = in_sizes[5];
    const int T = in_sizes[7];
    const int NB = (N + 255) / 256;    // 782 buckets
    const int chunk = (E + NBLK - 1) / NBLK;

    float* out = (float*)d_out;

    // Workspace layout (bytes):
    //  hb  bf16 [N][64] | h0/h1/h2 bf16 [N][32] | u bf16 [N][64]
    //  z f32 [N][128]  (CSR int scratch aliases z; dead by k_mlp)
    //  flags char[N] | list int[N] | cnt int
    char* W = (char*)d_ws;
    u16*   hb = (u16*)W;
    u16*   h0 = (u16*)(W + (size_t)N * 64 * 2);
    u16*   h1 = h0 + (size_t)N * 32;
    u16*   h2 = h1 + (size_t)N * 32;
    u16*   u  = (u16*)(W + (size_t)N * 64 * 2 + (size_t)N * 32 * 2 * 3);
    float* z  = (float*)(u + (size_t)N * 64);
    unsigned char* flags = (unsigned char*)(z + (size_t)N * 128);
    int*   list = (int*)(flags + (size_t)N);
    int*   cnt  = list + N;

    unsigned* bpk    = (unsigned*)z;
    int*      hist   = (int*)(bpk + E);
    int*      basep  = hist + NBLK * MAXB;
    int*      colsum = basep + NBLK * MAXB;
    int*      bb     = colsum + NB;

    const int hbBlocks   = (N + 63) / 64;
    const int postBlocks = (N + 127) / 128;
    const int mlpBlocks  = (N + 63) / 64;

    // ---- referenced-node flags + compaction ----
    k_zerof<<<(N / 4 + 255) / 256, 256, 0, stream>>>((int*)flags, N / 4, cnt);
    k_flags<<<(2 * U + 2 * T + 255) / 256, 256, 0, stream>>>(ui, ii, tes, ted, U, T, flags);
    k_compact<<<NB, 256, 0, stream>>>(flags, list, cnt, N);

    // ---- bucketed edge partition (by dst) ----
    k_bhist2<<<NBLK, 256, 0, stream>>>(dst, hist, E, NB, chunk);
    k_colscan<<<NB, 256, 0, stream>>>(hist, basep, colsum, NB);
    k_bscan2<<<1, 1024, 0, stream>>>(colsum, bb, NB, E);
    k_bscatter2<<<NBLK, 256, 0, stream>>>(src, dst, et, basep, bb, bpk, E, NB, chunk);

    // ---- layer 0 (MFMA GEMM + push-per-bucket aggregate) ----
    k_hb<<<hbBlocks, 256, 0, stream>>>(x, V0, loop0, b0, hb, h0, N);
    k_pull0<<<NB, 256, 0, stream>>>(bb, bpk, comb0, hb, h0, N);

    // ---- layer 1 ----
    k_pull_u<<<NB, 256, 0, stream>>>(bb, bpk, comb1, h0, u, N);
    k_post<<<postBlocks, 256, 0, stream>>>(u, h0, V1, loop1, b1, h1, N);

    // ---- layer 2 ----
    k_pull_u<<<NB, 256, 0, stream>>>(bb, bpk, comb2, h1, u, N);
    k_post<<<postBlocks, 256, 0, stream>>>(u, h1, V2, loop2, b2, h2, N);

    // ---- heads + reparameterization (compacted) ----
    k_mlp<<<mlpBlocks, 256, 0, stream>>>(h0, h1, h2, Wm1, bm1, Wm2, bm2,
                                         Ws1, bs1, Ws2, bs2, noise, z, list, cnt);
    // ---- outputs ----
    k_pairs<<<(U * 64 + 255) / 256, 256, 0, stream>>>(z, ui, ii, out, U, T);
    k_preds<<<(T * 64 + 255) / 256, 256, 0, stream>>>(z, tes, ted, out, U, T);
}

// Round 13
// 619.818 us; speedup vs baseline: 6.0473x; 6.0473x over previous
//
#include <hip/hip_runtime.h>
#include <hip/hip_bf16.h>

// N=200000, E=3200000, R=8, B=2, IN=128, H=32, OUT=128, U=10000, T=50000.

typedef float f4 __attribute__((ext_vector_type(4)));
typedef short s8 __attribute__((ext_vector_type(8)));   // 8 bf16 = 4 VGPRs (MFMA frag)
typedef unsigned short u16;
typedef u16 us4 __attribute__((ext_vector_type(4)));   // 4 bf16 = 8 bytes

__device__ inline u16 f2b(float f) {
    __hip_bfloat16 h = __float2bfloat16(f);
    return __builtin_bit_cast(u16, h);
}
__device__ inline float b2f(u16 s) {
    return __bfloat162float(__builtin_bit_cast(__hip_bfloat16, s));
}
__device__ inline f4 b4f(us4 v) {
    f4 r = {b2f(v.x), b2f(v.y), b2f(v.z), b2f(v.w)};
    return r;
}
__device__ inline float blo(unsigned v) { return b2f((u16)(v & 0xffffu)); }
__device__ inline float bhi(unsigned v) { return b2f((u16)(v >> 16)); }
__device__ inline unsigned bpack(float a, float b) {
    return (unsigned)f2b(a) | ((unsigned)f2b(b) << 16);
}

#define NBLK 256      // scatter blocks
#define MAXB 800      // >= NB = ceil(N/256) = 782
#define PADK 136      // 128 + 8 bf16 pad (k_hb LDS)

// ---------------------------------------------------------------------------
// Layer-0 basis+selfloop GEMM on MFMA (round-11 version, verified).
__global__ __launch_bounds__(256, 3)
void k_hb(const float* __restrict__ x, const float* __restrict__ V,
          const float* __restrict__ loopw, const float* __restrict__ bias,
          u16* __restrict__ hb, u16* __restrict__ agg, int nNodes)
{
    __shared__ u16 XA[64 * PADK];
    __shared__ u16 WB[96 * PADK];
    __shared__ float sbias[32];

    const int t = threadIdx.x;
    const int base = blockIdx.x * 64;

    if (t < 32) sbias[t] = bias[t];
    for (int i = t; i < 3072; i += 256) {
        if (i < 2048) {
            f4 v = *(const f4*)(V + (long)i * 4);
            int b = i >> 10, k = (i >> 3) & 127, o0 = (i & 7) * 4;
            int col = b * 32 + o0;
            #pragma unroll
            for (int s = 0; s < 4; ++s) WB[(col + s) * PADK + k] = f2b(v[s]);
        } else {
            int j = i - 2048;
            f4 v = *(const f4*)(loopw + (long)j * 4);
            int k = j >> 3, o0 = (j & 7) * 4;
            int col = 64 + o0;
            #pragma unroll
            for (int s = 0; s < 4; ++s) WB[(col + s) * PADK + k] = f2b(v[s]);
        }
    }
    for (int i = t; i < 2048; i += 256) {
        int row = i >> 5, c4 = i & 31;
        long gr = (long)min(base + row, nNodes - 1);
        f4 xv = *(const f4*)(x + gr * 128 + (long)c4 * 4);
        us4 v = {f2b(xv[0]), f2b(xv[1]), f2b(xv[2]), f2b(xv[3])};
        *(us4*)&XA[row * PADK + c4 * 4] = v;
    }
    __syncthreads();

    const int w    = t >> 6;
    const int l    = t & 63;
    const int rsel = l & 15;
    const int kg   = l >> 4;

    f4 acc[6] = {};
    for (int ks = 0; ks < 4; ++ks) {
        s8 a = *(const s8*)&XA[(w * 16 + rsel) * PADK + ks * 32 + kg * 8];
        #pragma unroll
        for (int ct = 0; ct < 6; ++ct) {
            s8 b = *(const s8*)&WB[(ct * 16 + rsel) * PADK + ks * 32 + kg * 8];
            acc[ct] = __builtin_amdgcn_mfma_f32_16x16x32_bf16(a, b, acc[ct], 0, 0, 0);
        }
    }

    #pragma unroll
    for (int ct = 0; ct < 6; ++ct) {
        int col = ct * 16 + rsel;
        #pragma unroll
        for (int r = 0; r < 4; ++r) {
            int node = base + w * 16 + kg * 4 + r;
            if (node < nNodes) {
                float v = acc[ct][r];
                if (col < 64) hb[(long)node * 64 + col] = f2b(v);
                else          agg[(long)node * 32 + (col - 64)] = f2b(v + sbias[col - 64]);
            }
        }
    }
}

// ---------------------------------------------------------------------------
// Contention-free bucketed CSR build (round-11 version).
__global__ __launch_bounds__(256)
void k_bhist2(const int* __restrict__ dst, int* __restrict__ hist,
              int nEdges, int nB, int chunk)
{
    __shared__ int hloc[MAXB];
    for (int i = threadIdx.x; i < nB; i += 256) hloc[i] = 0;
    __syncthreads();
    const int ebeg = blockIdx.x * chunk;
    const int eend = min(ebeg + chunk, nEdges);
    for (int e = ebeg + threadIdx.x; e < eend; e += 256)
        atomicAdd(&hloc[dst[e] >> 8], 1);
    __syncthreads();
    for (int i = threadIdx.x; i < nB; i += 256)
        hist[blockIdx.x * MAXB + i] = hloc[i];
}

__global__ __launch_bounds__(256)
void k_colscan(const int* __restrict__ hist, int* __restrict__ base,
               int* __restrict__ colsum, int nB)
{
    __shared__ int s[256];
    const int b = blockIdx.x;
    const int t = threadIdx.x;
    int v = hist[t * MAXB + b];
    s[t] = v; __syncthreads();
    for (int off = 1; off < 256; off <<= 1) {
        int tmp = (t >= off) ? s[t - off] : 0;
        __syncthreads();
        s[t] += tmp;
        __syncthreads();
    }
    base[t * MAXB + b] = s[t] - v;
    if (t == 255) colsum[b] = s[255];
}

__global__ __launch_bounds__(1024)
void k_bscan2(const int* __restrict__ colsum, int* __restrict__ bb,
              int* __restrict__ rowptr, int nB, int nNodes, int nEdges)
{
    __shared__ int s[1024];
    int t = threadIdx.x;
    int v = (t < nB) ? colsum[t] : 0;
    s[t] = v; __syncthreads();
    for (int off = 1; off < 1024; off <<= 1) {
        int tmp = (t >= off) ? s[t - off] : 0;
        __syncthreads();
        s[t] += tmp;
        __syncthreads();
    }
    if (t < nB) bb[t] = s[t] - v;
    if (t == 0) { bb[nB] = nEdges; rowptr[nNodes] = nEdges; }
}

__global__ __launch_bounds__(256)
void k_bscatter2(const int* __restrict__ src, const int* __restrict__ dst,
                 const int* __restrict__ et, const int* __restrict__ base,
                 const int* __restrict__ bb, unsigned* __restrict__ bpk,
                 int nEdges, int nB, int chunk)
{
    __shared__ int sbase[MAXB];
    __shared__ int cur[MAXB];
    for (int i = threadIdx.x; i < nB; i += 256) {
        sbase[i] = bb[i] + base[blockIdx.x * MAXB + i];
        cur[i] = 0;
    }
    __syncthreads();
    const int ebeg = blockIdx.x * chunk;
    const int eend = min(ebeg + chunk, nEdges);
    for (int e = ebeg + threadIdx.x; e < eend; e += 256) {
        int d = dst[e];
        int b = d >> 8;
        int r = atomicAdd(&cur[b], 1);
        bpk[sbase[b] + r] = ((unsigned)(d & 255) << 21)
                          | ((unsigned)src[e] << 3) | (unsigned)et[e];
    }
}

__global__ __launch_bounds__(256)
void k_bucket(const unsigned* __restrict__ bpk, const int* __restrict__ bbase,
              int* __restrict__ rowptr, unsigned* __restrict__ packed, int nNodes)
{
    __shared__ int s[256];
    __shared__ int cur[256];
    const int b = blockIdx.x;
    const int t = threadIdx.x;
    const int ebeg = bbase[b], eend = bbase[b + 1];

    cur[t] = 0;
    __syncthreads();
    for (int j = ebeg + t; j < eend; j += 256)
        atomicAdd(&cur[bpk[j] >> 21], 1);
    __syncthreads();
    int v = cur[t];
    s[t] = v; __syncthreads();
    for (int off = 1; off < 256; off <<= 1) {
        int tmp = (t >= off) ? s[t - off] : 0;
        __syncthreads();
        s[t] += tmp;
        __syncthreads();
    }
    int ex = s[t] - v;
    int node = b * 256 + t;
    if (node < nNodes) rowptr[node] = ebeg + ex;
    cur[t] = ex;
    __syncthreads();
    for (int j = ebeg + t; j < eend; j += 256) {
        unsigned p = bpk[j];
        int pos = ebeg + atomicAdd(&cur[p >> 21], 1);
        packed[pos] = p & 0x1FFFFFu;
    }
}

// ---------------------------------------------------------------------------
// Referenced-node set: flags + compaction.
__global__ __launch_bounds__(256)
void k_zerof(int* __restrict__ flags4, int n4, int* __restrict__ cnt)
{
    int i = blockIdx.x * 256 + threadIdx.x;
    if (i < n4) flags4[i] = 0;
    if (i == 0) *cnt = 0;
}

__global__ __launch_bounds__(256)
void k_flags(const int* __restrict__ ui, const int* __restrict__ ii,
             const int* __restrict__ tes, const int* __restrict__ ted,
             int U, int T, unsigned char* __restrict__ flags)
{
    int g = blockIdx.x * 256 + threadIdx.x;
    int idx;
    if (g < U)               idx = ui[g];
    else if (g < 2 * U)      idx = ii[g - U];
    else if (g < 2 * U + T)  idx = tes[g - 2 * U];
    else if (g < 2 * U + 2 * T) idx = ted[g - 2 * U - T];
    else return;
    flags[idx] = 1;
}

__global__ __launch_bounds__(256)
void k_compact(const unsigned char* __restrict__ flags, int* __restrict__ list,
               int* __restrict__ cnt, int n)
{
    __shared__ int s[256];
    __shared__ int bofs;
    int t = threadIdx.x;
    int i = blockIdx.x * 256 + t;
    int f = (i < n) ? (int)flags[i] : 0;
    s[t] = f; __syncthreads();
    for (int off = 1; off < 256; off <<= 1) {
        int v = (t >= off) ? s[t - off] : 0;
        __syncthreads();
        s[t] += v;
        __syncthreads();
    }
    if (t == 255) bofs = atomicAdd(cnt, s[255]);
    __syncthreads();
    if (f) list[bofs + s[t] - 1] = i;
}

// ---------------------------------------------------------------------------
// Layer-0 pull, pair-packed (round-11 version — best measured).
__global__ __launch_bounds__(256)
void k_pull0(const int* __restrict__ rowptr, const unsigned* __restrict__ packed,
             const float* __restrict__ comb, const u16* __restrict__ hb,
             u16* __restrict__ h0, int nNodes)
{
    __shared__ float sc[16];
    if (threadIdx.x < 16) sc[threadIdx.x] = comb[threadIdx.x];
    __syncthreads();
    int n = blockIdx.x * 4 + (threadIdx.x >> 6);
    if (n >= nNodes) return;
    const int lane = threadIdx.x & 63;
    const int half = lane >> 5;
    const int sub  = (lane >> 4) & 1;
    const int i2   = lane & 15;
    const long off = (long)sub * 32 + 2 * i2;
    int beg = rowptr[n], end = rowptr[n + 1];
    float a0 = 0.f, a1 = 0.f;
    int j = beg + half;
    for (; j + 2 < end; j += 4) {
        unsigned pa = packed[j], pb = packed[j + 2];
        unsigned va = *(const unsigned*)(hb + (long)(pa >> 3) * 64 + off);
        unsigned vb = *(const unsigned*)(hb + (long)(pb >> 3) * 64 + off);
        float ca = sc[(pa & 7) * 2 + sub];
        float cb = sc[(pb & 7) * 2 + sub];
        a0 = fmaf(ca, blo(va), a0);  a1 = fmaf(ca, bhi(va), a1);
        a0 = fmaf(cb, blo(vb), a0);  a1 = fmaf(cb, bhi(vb), a1);
    }
    if (j < end) {
        unsigned pa = packed[j];
        unsigned va = *(const unsigned*)(hb + (long)(pa >> 3) * 64 + off);
        float ca = sc[(pa & 7) * 2 + sub];
        a0 = fmaf(ca, blo(va), a0);  a1 = fmaf(ca, bhi(va), a1);
    }
    a0 += __shfl_xor(a0, 16);  a1 += __shfl_xor(a1, 16);
    a0 += __shfl_xor(a0, 32);  a1 += __shfl_xor(a1, 32);
    if (lane < 16) {
        unsigned* p = (unsigned*)(h0 + (long)n * 32 + 2 * i2);
        unsigned cur = *p;
        *p = bpack(tanhf(blo(cur) + a0), tanhf(bhi(cur) + a1));
    }
}

// ---------------------------------------------------------------------------
// Layer-1 pull (all nodes), pair-packed (round-11 version).
__global__ __launch_bounds__(256)
void k_pull_u(const int* __restrict__ rowptr, const unsigned* __restrict__ packed,
              const float* __restrict__ comb, const u16* __restrict__ hsrc,
              u16* __restrict__ u, int nNodes)
{
    __shared__ float sc[16];
    if (threadIdx.x < 16) sc[threadIdx.x] = comb[threadIdx.x];
    __syncthreads();
    int n = blockIdx.x * 4 + (threadIdx.x >> 6);
    if (n >= nNodes) return;
    const int lane = threadIdx.x & 63;
    const int grp  = lane >> 4;
    const int i2   = lane & 15;
    int beg = rowptr[n], end = rowptr[n + 1];
    float u00 = 0.f, u01 = 0.f, u10 = 0.f, u11 = 0.f;
    int j = beg + grp;
    for (; j + 4 < end; j += 8) {
        unsigned pa = packed[j], pb = packed[j + 4];
        unsigned va = *(const unsigned*)(hsrc + (long)(pa >> 3) * 32 + 2 * i2);
        unsigned vb = *(const unsigned*)(hsrc + (long)(pb >> 3) * 32 + 2 * i2);
        int ra = (pa & 7) * 2, rb = (pb & 7) * 2;
        float c0a = sc[ra], c1a = sc[ra + 1];
        float c0b = sc[rb], c1b = sc[rb + 1];
        float alo = blo(va), ahi = bhi(va);
        float blo_ = blo(vb), bhi_ = bhi(vb);
        u00 = fmaf(c0a, alo, u00);  u01 = fmaf(c0a, ahi, u01);
        u10 = fmaf(c1a, alo, u10);  u11 = fmaf(c1a, ahi, u11);
        u00 = fmaf(c0b, blo_, u00); u01 = fmaf(c0b, bhi_, u01);
        u10 = fmaf(c1b, blo_, u10); u11 = fmaf(c1b, bhi_, u11);
    }
    if (j < end) {
        unsigned pa = packed[j];
        unsigned va = *(const unsigned*)(hsrc + (long)(pa >> 3) * 32 + 2 * i2);
        int ra = (pa & 7) * 2;
        float c0a = sc[ra], c1a = sc[ra + 1];
        float alo = blo(va), ahi = bhi(va);
        u00 = fmaf(c0a, alo, u00);  u01 = fmaf(c0a, ahi, u01);
        u10 = fmaf(c1a, alo, u10);  u11 = fmaf(c1a, ahi, u11);
    }
    u00 += __shfl_xor(u00, 16);  u01 += __shfl_xor(u01, 16);
    u10 += __shfl_xor(u10, 16);  u11 += __shfl_xor(u11, 16);
    u00 += __shfl_xor(u00, 32);  u01 += __shfl_xor(u01, 32);
    u10 += __shfl_xor(u10, 32);  u11 += __shfl_xor(u11, 32);
    if (lane < 16) {
        unsigned* p0 = (unsigned*)(u + (long)n * 64 + 2 * i2);
        unsigned* p1 = (unsigned*)(u + (long)n * 64 + 32 + 2 * i2);
        *p0 = bpack(u00, u01);
        *p1 = bpack(u10, u11);
    }
}

// ---------------------------------------------------------------------------
// Layer-2 pull over REFERENCED nodes only (n = list[idx]).
__global__ __launch_bounds__(256)
void k_pull_uf(const int* __restrict__ rowptr, const unsigned* __restrict__ packed,
               const float* __restrict__ comb, const u16* __restrict__ hsrc,
               u16* __restrict__ u, const int* __restrict__ list,
               const int* __restrict__ cnt)
{
    __shared__ float sc[16];
    if (threadIdx.x < 16) sc[threadIdx.x] = comb[threadIdx.x];
    __syncthreads();
    const int count = *cnt;
    int idx = blockIdx.x * 4 + (threadIdx.x >> 6);
    if (idx >= count) return;
    const int n = list[idx];
    const int lane = threadIdx.x & 63;
    const int grp  = lane >> 4;
    const int i2   = lane & 15;
    int beg = rowptr[n], end = rowptr[n + 1];
    float u00 = 0.f, u01 = 0.f, u10 = 0.f, u11 = 0.f;
    int j = beg + grp;
    for (; j + 4 < end; j += 8) {
        unsigned pa = packed[j], pb = packed[j + 4];
        unsigned va = *(const unsigned*)(hsrc + (long)(pa >> 3) * 32 + 2 * i2);
        unsigned vb = *(const unsigned*)(hsrc + (long)(pb >> 3) * 32 + 2 * i2);
        int ra = (pa & 7) * 2, rb = (pb & 7) * 2;
        float c0a = sc[ra], c1a = sc[ra + 1];
        float c0b = sc[rb], c1b = sc[rb + 1];
        float alo = blo(va), ahi = bhi(va);
        float blo_ = blo(vb), bhi_ = bhi(vb);
        u00 = fmaf(c0a, alo, u00);  u01 = fmaf(c0a, ahi, u01);
        u10 = fmaf(c1a, alo, u10);  u11 = fmaf(c1a, ahi, u11);
        u00 = fmaf(c0b, blo_, u00); u01 = fmaf(c0b, bhi_, u01);
        u10 = fmaf(c1b, blo_, u10); u11 = fmaf(c1b, bhi_, u11);
    }
    if (j < end) {
        unsigned pa = packed[j];
        unsigned va = *(const unsigned*)(hsrc + (long)(pa >> 3) * 32 + 2 * i2);
        int ra = (pa & 7) * 2;
        float c0a = sc[ra], c1a = sc[ra + 1];
        float alo = blo(va), ahi = bhi(va);
        u00 = fmaf(c0a, alo, u00);  u01 = fmaf(c0a, ahi, u01);
        u10 = fmaf(c1a, alo, u10);  u11 = fmaf(c1a, ahi, u11);
    }
    u00 += __shfl_xor(u00, 16);  u01 += __shfl_xor(u01, 16);
    u10 += __shfl_xor(u10, 16);  u11 += __shfl_xor(u11, 16);
    u00 += __shfl_xor(u00, 32);  u01 += __shfl_xor(u01, 32);
    u10 += __shfl_xor(u10, 32);  u11 += __shfl_xor(u11, 32);
    if (lane < 16) {
        unsigned* p0 = (unsigned*)(u + (long)n * 64 + 2 * i2);
        unsigned* p1 = (unsigned*)(u + (long)n * 64 + 32 + 2 * i2);
        *p0 = bpack(u00, u01);
        *p1 = bpack(u10, u11);
    }
}

// ---------------------------------------------------------------------------
// Post GEMM for layer 1 (all nodes — round-11 version).
__global__ __launch_bounds__(256, 2)
void k_post(const u16* __restrict__ u, const u16* __restrict__ hsrc,
            const float* __restrict__ V, const float* __restrict__ loopw,
            const float* __restrict__ bias, u16* __restrict__ hdst, int nNodes)
{
    __shared__ float CW[96 * 32];
    for (int idx = threadIdx.x; idx < 96 * 32; idx += 256) {
        int i = idx / 32, o = idx % 32;
        CW[idx] = (i < 64) ? V[i * 32 + o]
                           : loopw[(i - 64) * 32 + o];
    }
    __syncthreads();

    const int cg = threadIdx.x & 7;
    const int ng = threadIdx.x >> 3;
    const int c0 = cg * 4;
    const int base = blockIdx.x * 128 + ng * 4;
    if (base >= nNodes) return;

    long rows[4];
    #pragma unroll
    for (int j = 0; j < 4; ++j)
        rows[j] = (long)min(base + j, nNodes - 1);

    float acc[4][4] = {};
    #pragma unroll 2
    for (int i = 0; i < 96; i += 4) {
        f4 w0 = *(const f4*)&CW[(i + 0) * 32 + c0];
        f4 w1 = *(const f4*)&CW[(i + 1) * 32 + c0];
        f4 w2 = *(const f4*)&CW[(i + 2) * 32 + c0];
        f4 w3 = *(const f4*)&CW[(i + 3) * 32 + c0];
        #pragma unroll
        for (int j = 0; j < 4; ++j) {
            f4 hv;
            if (i < 64) hv = b4f(*(const us4*)(u + rows[j] * 64 + i));
            else        hv = b4f(*(const us4*)(hsrc + rows[j] * 32 + (i - 64)));
            #pragma unroll
            for (int q = 0; q < 4; ++q)
                acc[j][q] = fmaf(hv[3], w3[q],
                            fmaf(hv[2], w2[q],
                            fmaf(hv[1], w1[q],
                            fmaf(hv[0], w0[q], acc[j][q]))));
        }
    }

    f4 bv = *(const f4*)(bias + c0);
    #pragma unroll
    for (int j = 0; j < 4; ++j)
        if (base + j < nNodes) {
            us4 v = {f2b(tanhf(acc[j][0] + bv[0])), f2b(tanhf(acc[j][1] + bv[1])),
                     f2b(tanhf(acc[j][2] + bv[2])), f2b(tanhf(acc[j][3] + bv[3]))};
            *(us4*)(hdst + (long)(base + j) * 32 + c0) = v;
        }
}

// ---------------------------------------------------------------------------
// Post GEMM for layer 2 over REFERENCED nodes only.
__global__ __launch_bounds__(256, 2)
void k_postf(const u16* __restrict__ u, const u16* __restrict__ hsrc,
             const float* __restrict__ V, const float* __restrict__ loopw,
             const float* __restrict__ bias, u16* __restrict__ hdst,
             const int* __restrict__ list, const int* __restrict__ cnt)
{
    __shared__ float CW[96 * 32];
    for (int idx = threadIdx.x; idx < 96 * 32; idx += 256) {
        int i = idx / 32, o = idx % 32;
        CW[idx] = (i < 64) ? V[i * 32 + o]
                           : loopw[(i - 64) * 32 + o];
    }
    __syncthreads();

    const int count = *cnt;
    const int cg = threadIdx.x & 7;
    const int ng = threadIdx.x >> 3;
    const int c0 = cg * 4;
    const int base = blockIdx.x * 128 + ng * 4;
    if (base >= count) return;

    long rows[4];
    #pragma unroll
    for (int j = 0; j < 4; ++j)
        rows[j] = (long)list[min(base + j, count - 1)];

    float acc[4][4] = {};
    #pragma unroll 2
    for (int i = 0; i < 96; i += 4) {
        f4 w0 = *(const f4*)&CW[(i + 0) * 32 + c0];
        f4 w1 = *(const f4*)&CW[(i + 1) * 32 + c0];
        f4 w2 = *(const f4*)&CW[(i + 2) * 32 + c0];
        f4 w3 = *(const f4*)&CW[(i + 3) * 32 + c0];
        #pragma unroll
        for (int j = 0; j < 4; ++j) {
            f4 hv;
            if (i < 64) hv = b4f(*(const us4*)(u + rows[j] * 64 + i));
            else        hv = b4f(*(const us4*)(hsrc + rows[j] * 32 + (i - 64)));
            #pragma unroll
            for (int q = 0; q < 4; ++q)
                acc[j][q] = fmaf(hv[3], w3[q],
                            fmaf(hv[2], w2[q],
                            fmaf(hv[1], w1[q],
                            fmaf(hv[0], w0[q], acc[j][q]))));
        }
    }

    f4 bv = *(const f4*)(bias + c0);
    #pragma unroll
    for (int j = 0; j < 4; ++j)
        if (base + j < count) {
            us4 v = {f2b(tanhf(acc[j][0] + bv[0])), f2b(tanhf(acc[j][1] + bv[1])),
                     f2b(tanhf(acc[j][2] + bv[2])), f2b(tanhf(acc[j][3] + bv[3]))};
            *(us4*)(hdst + rows[j] * 32 + c0) = v;
        }
}

// ---------------------------------------------------------------------------
// Fused MLP heads + reparameterization over the COMPACTED node list only.
__global__ __launch_bounds__(256, 2)
void k_mlp(const u16* __restrict__ h0, const u16* __restrict__ h1,
           const u16* __restrict__ h2,
           const float* __restrict__ Wm1, const float* __restrict__ bm1,
           const float* __restrict__ Wm2, const float* __restrict__ bm2,
           const float* __restrict__ Ws1, const float* __restrict__ bs1,
           const float* __restrict__ Ws2, const float* __restrict__ bs2,
           const float* __restrict__ noise, float* __restrict__ z,
           const int* __restrict__ list, const int* __restrict__ cnt)
{
    const int count = *cnt;
    const int base = blockIdx.x * 64;
    if (base >= count) return;

    __shared__ float sW1[2][96 * 32];
    __shared__ float sW2[2][32 * 128];
    __shared__ float sb1[2][32];
    __shared__ float sb2[2][128];
    __shared__ float shid[2][64][32];

    for (int i = threadIdx.x; i < 96 * 32; i += 256) { sW1[0][i] = Wm1[i]; sW1[1][i] = Ws1[i]; }
    for (int i = threadIdx.x; i < 32 * 128; i += 256) { sW2[0][i] = Wm2[i]; sW2[1][i] = Ws2[i]; }
    if (threadIdx.x < 32)  { sb1[0][threadIdx.x] = bm1[threadIdx.x]; sb1[1][threadIdx.x] = bs1[threadIdx.x]; }
    if (threadIdx.x < 128) { sb2[0][threadIdx.x] = bm2[threadIdx.x]; sb2[1][threadIdx.x] = bs2[threadIdx.x]; }
    __syncthreads();

    // ---- phase A: hidden = relu(cs @ W1 + b1) ----
    {
        const int head = threadIdx.x >> 7;
        const int rem  = threadIdx.x & 127;
        const int ng   = rem >> 3;
        const int c0   = (rem & 7) * 4;
        const float* sW = sW1[head];
        long rows[4];
        #pragma unroll
        for (int j = 0; j < 4; ++j)
            rows[j] = (long)list[min(base + ng * 4 + j, count - 1)];

        float acc[4][4] = {};
        const u16* hs[3] = {h0, h1, h2};
        #pragma unroll
        for (int part = 0; part < 3; ++part) {
            const u16* hp = hs[part];
            #pragma unroll
            for (int kk = 0; kk < 32; kk += 4) {
                const int k = part * 32 + kk;
                f4 w0 = *(const f4*)&sW[(k + 0) * 32 + c0];
                f4 w1 = *(const f4*)&sW[(k + 1) * 32 + c0];
                f4 w2 = *(const f4*)&sW[(k + 2) * 32 + c0];
                f4 w3 = *(const f4*)&sW[(k + 3) * 32 + c0];
                #pragma unroll
                for (int j = 0; j < 4; ++j) {
                    f4 hv = b4f(*(const us4*)(hp + rows[j] * 32 + kk));
                    #pragma unroll
                    for (int q = 0; q < 4; ++q)
                        acc[j][q] = fmaf(hv[3], w3[q],
                                    fmaf(hv[2], w2[q],
                                    fmaf(hv[1], w1[q],
                                    fmaf(hv[0], w0[q], acc[j][q]))));
                }
            }
        }
        f4 bv = *(const f4*)&sb1[head][c0];
        #pragma unroll
        for (int j = 0; j < 4; ++j) {
            f4 v = {fmaxf(acc[j][0] + bv[0], 0.f), fmaxf(acc[j][1] + bv[1], 0.f),
                    fmaxf(acc[j][2] + bv[2], 0.f), fmaxf(acc[j][3] + bv[3], 0.f)};
            *(f4*)&shid[head][ng * 4 + j][c0] = v;
        }
    }
    __syncthreads();

    // ---- phase B: out = hid @ W2 + b2; z = mean + noise * exp(log_std) ----
    const int ng = threadIdx.x >> 5;
    const int c0 = (threadIdx.x & 31) * 4;
    #pragma unroll
    for (int pass = 0; pass < 2; ++pass) {
        const int nb = pass * 32 + ng * 4;
        float am[4][4] = {}, as_[4][4] = {};
        #pragma unroll 4
        for (int k = 0; k < 32; k += 4) {
            f4 wm0 = *(const f4*)&sW2[0][(k + 0) * 128 + c0];
            f4 wm1 = *(const f4*)&sW2[0][(k + 1) * 128 + c0];
            f4 wm2 = *(const f4*)&sW2[0][(k + 2) * 128 + c0];
            f4 wm3 = *(const f4*)&sW2[0][(k + 3) * 128 + c0];
            f4 ws0 = *(const f4*)&sW2[1][(k + 0) * 128 + c0];
            f4 ws1 = *(const f4*)&sW2[1][(k + 1) * 128 + c0];
            f4 ws2 = *(const f4*)&sW2[1][(k + 2) * 128 + c0];
            f4 ws3 = *(const f4*)&sW2[1][(k + 3) * 128 + c0];
            #pragma unroll
            for (int j = 0; j < 4; ++j) {
                f4 hm = *(const f4*)&shid[0][nb + j][k];
                f4 hv = *(const f4*)&shid[1][nb + j][k];
                #pragma unroll
                for (int q = 0; q < 4; ++q) {
                    am[j][q]  = fmaf(hm[3], wm3[q],
                                fmaf(hm[2], wm2[q],
                                fmaf(hm[1], wm1[q],
                                fmaf(hm[0], wm0[q], am[j][q]))));
                    as_[j][q] = fmaf(hv[3], ws3[q],
                                fmaf(hv[2], ws2[q],
                                fmaf(hv[1], ws1[q],
                                fmaf(hv[0], ws0[q], as_[j][q]))));
                }
            }
        }
        f4 b2m = *(const f4*)&sb2[0][c0];
        f4 b2s = *(const f4*)&sb2[1][c0];
        #pragma unroll
        for (int j = 0; j < 4; ++j) {
            const int idx = base + nb + j;
            if (idx < count) {
                const long n = (long)list[idx];
                f4 nz = *(const f4*)(noise + n * 128 + c0);
                f4 v;
                #pragma unroll
                for (int q = 0; q < 4; ++q)
                    v[q] = fmaf(nz[q], expf(as_[j][q] + b2s[q]), am[j][q] + b2m[q]);
                *(f4*)(z + n * 128 + c0) = v;
            }
        }
    }
}

// ---------------------------------------------------------------------------
__global__ __launch_bounds__(256)
void k_pairs(const float* __restrict__ z, const int* __restrict__ ui,
             const int* __restrict__ ii, float* __restrict__ out, int U, int T)
{
    int w = (blockIdx.x * 256 + threadIdx.x) >> 6;
    int lane = threadIdx.x & 63;
    if (w >= U) return;
    int a = ui[w], b = ii[w];
    float a0 = z[(long)a * 128 + lane], a1 = z[(long)a * 128 + 64 + lane];
    float b0 = z[(long)b * 128 + lane], b1 = z[(long)b * 128 + 64 + lane];
    float* res = out + U + T;
    res[(long)w * 128 + lane] = a0;
    res[(long)w * 128 + 64 + lane] = a1;
    res[(long)(U + w) * 128 + lane] = b0;
    res[(long)(U + w) * 128 + 64 + lane] = b1;
    float d = fmaf(a0, b0, a1 * b1);
    #pragma unroll
    for (int off = 32; off; off >>= 1) d += __shfl_xor(d, off);
    if (lane == 0) out[w] = d;
}

__global__ __launch_bounds__(256)
void k_preds(const float* __restrict__ z, const int* __restrict__ ts,
             const int* __restrict__ td, float* __restrict__ out, int U, int T)
{
    int w = (blockIdx.x * 256 + threadIdx.x) >> 6;
    int lane = threadIdx.x & 63;
    if (w >= T) return;
    int a = ts[w], b = td[w];
    float a0 = z[(long)a * 128 + lane], a1 = z[(long)a * 128 + 64 + lane];
    float b0 = z[(long)b * 128 + lane], b1 = z[(long)b * 128 + 64 + lane];
    float d = fmaf(a0, b0, a1 * b1);
    #pragma unroll
    for (int off = 32; off; off >>= 1) d += __shfl_xor(d, off);
    if (lane == 0) out[U + w] = d;
}

// ---------------------------------------------------------------------------
extern "C" void kernel_launch(void* const* d_in, const int* in_sizes, int n_in,
                              void* d_out, int out_size, void* d_ws, size_t ws_size,
                              hipStream_t stream)
{
    const float* x     = (const float*)d_in[0];
    const int*   src   = (const int*)d_in[1];
    const int*   dst   = (const int*)d_in[2];
    const int*   et    = (const int*)d_in[3];
    const float* noise = (const float*)d_in[4];
    const int*   ui    = (const int*)d_in[5];
    const int*   ii    = (const int*)d_in[6];
    const int*   tes   = (const int*)d_in[7];
    const int*   ted   = (const int*)d_in[8];
    const float* V0    = (const float*)d_in[9];
    const float* comb0 = (const float*)d_in[10];
    const float* loop0 = (const float*)d_in[11];
    const float* b0    = (const float*)d_in[12];
    const float* V1    = (const float*)d_in[13];
    const float* comb1 = (const float*)d_in[14];
    const float* loop1 = (const float*)d_in[15];
    const float* b1    = (const float*)d_in[16];
    const float* V2    = (const float*)d_in[17];
    const float* comb2 = (const float*)d_in[18];
    const float* loop2 = (const float*)d_in[19];
    const float* b2    = (const float*)d_in[20];
    const float* Wm1   = (const float*)d_in[21];
    const float* bm1   = (const float*)d_in[22];
    const float* Wm2   = (const float*)d_in[23];
    const float* bm2   = (const float*)d_in[24];
    const float* Ws1   = (const float*)d_in[25];
    const float* bs1   = (const float*)d_in[26];
    const float* Ws2   = (const float*)d_in[27];
    const float* bs2   = (const float*)d_in[28];

    const int N = in_sizes[0] / 128;   // 200000
    const int E = in_sizes[1];         // 3200000
    const int U = in_sizes[5];
    const int T = in_sizes[7];
    const int NB = (N + 255) / 256;    // 782 buckets
    const int chunk = (E + NBLK - 1) / NBLK;

    float* out = (float*)d_out;

    // Workspace layout (bytes):
    //  hb  bf16 [N][64] | h0/h1/h2 bf16 [N][32] | u bf16 [N][64]
    //  z f32 [N][128]  (CSR int scratch aliases z; dead by k_mlp)
    //  flags char[N] | list int[N] | cnt int
    char* W = (char*)d_ws;
    u16*   hb = (u16*)W;
    u16*   h0 = (u16*)(W + (size_t)N * 64 * 2);
    u16*   h1 = h0 + (size_t)N * 32;
    u16*   h2 = h1 + (size_t)N * 32;
    u16*   u  = (u16*)(W + (size_t)N * 64 * 2 + (size_t)N * 32 * 2 * 3);
    float* z  = (float*)(u + (size_t)N * 64);
    unsigned char* flags = (unsigned char*)(z + (size_t)N * 128);
    int*   list = (int*)(flags + (size_t)N);
    int*   cnt  = list + N;

    int*      rowptr = (int*)z;
    unsigned* packed = (unsigned*)(rowptr + N + 1);
    unsigned* bpk    = packed + E;
    int*      hist   = (int*)(bpk + E);
    int*      basep  = hist + NBLK * MAXB;
    int*      colsum = basep + NBLK * MAXB;
    int*      bb     = colsum + NB;

    const int hbBlocks   = (N + 63) / 64;
    const int pullBlocks = (N + 3) / 4;
    const int postBlocks = (N + 127) / 128;
    const int mlpBlocks  = (N + 63) / 64;

    // ---- referenced-node flags + compaction ----
    k_zerof<<<(N / 4 + 255) / 256, 256, 0, stream>>>((int*)flags, N / 4, cnt);
    k_flags<<<(2 * U + 2 * T + 255) / 256, 256, 0, stream>>>(ui, ii, tes, ted, U, T, flags);
    k_compact<<<NB, 256, 0, stream>>>(flags, list, cnt, N);

    // ---- contention-free bucketed CSR build (by dst) ----
    k_bhist2<<<NBLK, 256, 0, stream>>>(dst, hist, E, NB, chunk);
    k_colscan<<<NB, 256, 0, stream>>>(hist, basep, colsum, NB);
    k_bscan2<<<1, 1024, 0, stream>>>(colsum, bb, rowptr, NB, N, E);
    k_bscatter2<<<NBLK, 256, 0, stream>>>(src, dst, et, basep, bb, bpk, E, NB, chunk);
    k_bucket<<<NB, 256, 0, stream>>>(bpk, bb, rowptr, packed, N);

    // ---- layer 0 (MFMA GEMM + pull) ----
    k_hb<<<hbBlocks, 256, 0, stream>>>(x, V0, loop0, b0, hb, h0, N);
    k_pull0<<<pullBlocks, 256, 0, stream>>>(rowptr, packed, comb0, hb, h0, N);

    // ---- layer 1 (all nodes) ----
    k_pull_u<<<pullBlocks, 256, 0, stream>>>(rowptr, packed, comb1, h0, u, N);
    k_post<<<postBlocks, 256, 0, stream>>>(u, h0, V1, loop1, b1, h1, N);

    // ---- layer 2 (referenced nodes only) ----
    k_pull_uf<<<pullBlocks, 256, 0, stream>>>(rowptr, packed, comb2, h1, u, list, cnt);
    k_postf<<<postBlocks, 256, 0, stream>>>(u, h1, V2, loop2, b2, h2, list, cnt);

    // ---- heads + reparameterization (compacted) ----
    k_mlp<<<mlpBlocks, 256, 0, stream>>>(h0, h1, h2, Wm1, bm1, Wm2, bm2,
                                         Ws1, bs1, Ws2, bs2, noise, z, list, cnt);
    // ---- outputs ----
    k_pairs<<<(U * 64 + 255) / 256, 256, 0, stream>>>(z, ui, ii, out, U, T);
    k_preds<<<(T * 64 + 255) / 256, 256, 0, stream>>>(z, tes, ted, out, U, T);
}

// Round 14
// 589.844 us; speedup vs baseline: 6.3546x; 1.0508x over previous
//
#include <hip/hip_runtime.h>
#include <hip/hip_bf16.h>

// N=200000, E=3200000, R=8, B=2, IN=128, H=32, OUT=128, U=10000, T=50000.

typedef float f4 __attribute__((ext_vector_type(4)));
typedef short s8 __attribute__((ext_vector_type(8)));   // 8 bf16 = 4 VGPRs (MFMA frag)
typedef unsigned short u16;
typedef u16 us4 __attribute__((ext_vector_type(4)));   // 4 bf16 = 8 bytes

__device__ inline u16 f2b(float f) {
    __hip_bfloat16 h = __float2bfloat16(f);
    return __builtin_bit_cast(u16, h);
}
__device__ inline float b2f(u16 s) {
    return __bfloat162float(__builtin_bit_cast(__hip_bfloat16, s));
}
__device__ inline f4 b4f(us4 v) {
    f4 r = {b2f(v.x), b2f(v.y), b2f(v.z), b2f(v.w)};
    return r;
}
__device__ inline float blo(unsigned v) { return b2f((u16)(v & 0xffffu)); }
__device__ inline float bhi(unsigned v) { return b2f((u16)(v >> 16)); }
__device__ inline unsigned bpack(float a, float b) {
    return (unsigned)f2b(a) | ((unsigned)f2b(b) << 16);
}

#define NBLK 256      // scatter blocks
#define MAXB 800      // >= NB = ceil(N/256) = 782
#define PADK 136      // 128 + 8 bf16 pad (k_hb LDS)

// ---------------------------------------------------------------------------
// Layer-0 basis+selfloop GEMM on MFMA (round-11 version, verified).
__global__ __launch_bounds__(256, 3)
void k_hb(const float* __restrict__ x, const float* __restrict__ V,
          const float* __restrict__ loopw, const float* __restrict__ bias,
          u16* __restrict__ hb, u16* __restrict__ agg, int nNodes)
{
    __shared__ u16 XA[64 * PADK];
    __shared__ u16 WB[96 * PADK];
    __shared__ float sbias[32];

    const int t = threadIdx.x;
    const int base = blockIdx.x * 64;

    if (t < 32) sbias[t] = bias[t];
    for (int i = t; i < 3072; i += 256) {
        if (i < 2048) {
            f4 v = *(const f4*)(V + (long)i * 4);
            int b = i >> 10, k = (i >> 3) & 127, o0 = (i & 7) * 4;
            int col = b * 32 + o0;
            #pragma unroll
            for (int s = 0; s < 4; ++s) WB[(col + s) * PADK + k] = f2b(v[s]);
        } else {
            int j = i - 2048;
            f4 v = *(const f4*)(loopw + (long)j * 4);
            int k = j >> 3, o0 = (j & 7) * 4;
            int col = 64 + o0;
            #pragma unroll
            for (int s = 0; s < 4; ++s) WB[(col + s) * PADK + k] = f2b(v[s]);
        }
    }
    for (int i = t; i < 2048; i += 256) {
        int row = i >> 5, c4 = i & 31;
        long gr = (long)min(base + row, nNodes - 1);
        f4 xv = *(const f4*)(x + gr * 128 + (long)c4 * 4);
        us4 v = {f2b(xv[0]), f2b(xv[1]), f2b(xv[2]), f2b(xv[3])};
        *(us4*)&XA[row * PADK + c4 * 4] = v;
    }
    __syncthreads();

    const int w    = t >> 6;
    const int l    = t & 63;
    const int rsel = l & 15;
    const int kg   = l >> 4;

    f4 acc[6] = {};
    for (int ks = 0; ks < 4; ++ks) {
        s8 a = *(const s8*)&XA[(w * 16 + rsel) * PADK + ks * 32 + kg * 8];
        #pragma unroll
        for (int ct = 0; ct < 6; ++ct) {
            s8 b = *(const s8*)&WB[(ct * 16 + rsel) * PADK + ks * 32 + kg * 8];
            acc[ct] = __builtin_amdgcn_mfma_f32_16x16x32_bf16(a, b, acc[ct], 0, 0, 0);
        }
    }

    #pragma unroll
    for (int ct = 0; ct < 6; ++ct) {
        int col = ct * 16 + rsel;
        #pragma unroll
        for (int r = 0; r < 4; ++r) {
            int node = base + w * 16 + kg * 4 + r;
            if (node < nNodes) {
                float v = acc[ct][r];
                if (col < 64) hb[(long)node * 64 + col] = f2b(v);
                else          agg[(long)node * 32 + (col - 64)] = f2b(v + sbias[col - 64]);
            }
        }
    }
}

// ---------------------------------------------------------------------------
// Contention-free bucketed CSR build (round-11 version).
__global__ __launch_bounds__(256)
void k_bhist2(const int* __restrict__ dst, int* __restrict__ hist,
              int nEdges, int nB, int chunk)
{
    __shared__ int hloc[MAXB];
    for (int i = threadIdx.x; i < nB; i += 256) hloc[i] = 0;
    __syncthreads();
    const int ebeg = blockIdx.x * chunk;
    const int eend = min(ebeg + chunk, nEdges);
    for (int e = ebeg + threadIdx.x; e < eend; e += 256)
        atomicAdd(&hloc[dst[e] >> 8], 1);
    __syncthreads();
    for (int i = threadIdx.x; i < nB; i += 256)
        hist[blockIdx.x * MAXB + i] = hloc[i];
}

__global__ __launch_bounds__(256)
void k_colscan(const int* __restrict__ hist, int* __restrict__ base,
               int* __restrict__ colsum, int nB)
{
    __shared__ int s[256];
    const int b = blockIdx.x;
    const int t = threadIdx.x;
    int v = hist[t * MAXB + b];
    s[t] = v; __syncthreads();
    for (int off = 1; off < 256; off <<= 1) {
        int tmp = (t >= off) ? s[t - off] : 0;
        __syncthreads();
        s[t] += tmp;
        __syncthreads();
    }
    base[t * MAXB + b] = s[t] - v;
    if (t == 255) colsum[b] = s[255];
}

__global__ __launch_bounds__(1024)
void k_bscan2(const int* __restrict__ colsum, int* __restrict__ bb,
              int* __restrict__ rowptr, int nB, int nNodes, int nEdges)
{
    __shared__ int s[1024];
    int t = threadIdx.x;
    int v = (t < nB) ? colsum[t] : 0;
    s[t] = v; __syncthreads();
    for (int off = 1; off < 1024; off <<= 1) {
        int tmp = (t >= off) ? s[t - off] : 0;
        __syncthreads();
        s[t] += tmp;
        __syncthreads();
    }
    if (t < nB) bb[t] = s[t] - v;
    if (t == 0) { bb[nB] = nEdges; rowptr[nNodes] = nEdges; }
}

__global__ __launch_bounds__(256)
void k_bscatter2(const int* __restrict__ src, const int* __restrict__ dst,
                 const int* __restrict__ et, const int* __restrict__ base,
                 const int* __restrict__ bb, unsigned* __restrict__ bpk,
                 int nEdges, int nB, int chunk)
{
    __shared__ int sbase[MAXB];
    __shared__ int cur[MAXB];
    for (int i = threadIdx.x; i < nB; i += 256) {
        sbase[i] = bb[i] + base[blockIdx.x * MAXB + i];
        cur[i] = 0;
    }
    __syncthreads();
    const int ebeg = blockIdx.x * chunk;
    const int eend = min(ebeg + chunk, nEdges);
    for (int e = ebeg + threadIdx.x; e < eend; e += 256) {
        int d = dst[e];
        int b = d >> 8;
        int r = atomicAdd(&cur[b], 1);
        bpk[sbase[b] + r] = ((unsigned)(d & 255) << 21)
                          | ((unsigned)src[e] << 3) | (unsigned)et[e];
    }
}

__global__ __launch_bounds__(256)
void k_bucket(const unsigned* __restrict__ bpk, const int* __restrict__ bbase,
              int* __restrict__ rowptr, unsigned* __restrict__ packed, int nNodes)
{
    __shared__ int s[256];
    __shared__ int cur[256];
    const int b = blockIdx.x;
    const int t = threadIdx.x;
    const int ebeg = bbase[b], eend = bbase[b + 1];

    cur[t] = 0;
    __syncthreads();
    for (int j = ebeg + t; j < eend; j += 256)
        atomicAdd(&cur[bpk[j] >> 21], 1);
    __syncthreads();
    int v = cur[t];
    s[t] = v; __syncthreads();
    for (int off = 1; off < 256; off <<= 1) {
        int tmp = (t >= off) ? s[t - off] : 0;
        __syncthreads();
        s[t] += tmp;
        __syncthreads();
    }
    int ex = s[t] - v;
    int node = b * 256 + t;
    if (node < nNodes) rowptr[node] = ebeg + ex;
    cur[t] = ex;
    __syncthreads();
    for (int j = ebeg + t; j < eend; j += 256) {
        unsigned p = bpk[j];
        int pos = ebeg + atomicAdd(&cur[p >> 21], 1);
        packed[pos] = p & 0x1FFFFFu;
    }
}

// ---------------------------------------------------------------------------
// Referenced-node set: flags + compaction.
__global__ __launch_bounds__(256)
void k_zerof(int* __restrict__ flags4, int n4, int* __restrict__ cnt)
{
    int i = blockIdx.x * 256 + threadIdx.x;
    if (i < n4) flags4[i] = 0;
    if (i == 0) *cnt = 0;
}

__global__ __launch_bounds__(256)
void k_flags(const int* __restrict__ ui, const int* __restrict__ ii,
             const int* __restrict__ tes, const int* __restrict__ ted,
             int U, int T, unsigned char* __restrict__ flags)
{
    int g = blockIdx.x * 256 + threadIdx.x;
    int idx;
    if (g < U)               idx = ui[g];
    else if (g < 2 * U)      idx = ii[g - U];
    else if (g < 2 * U + T)  idx = tes[g - 2 * U];
    else if (g < 2 * U + 2 * T) idx = ted[g - 2 * U - T];
    else return;
    flags[idx] = 1;
}

__global__ __launch_bounds__(256)
void k_compact(const unsigned char* __restrict__ flags, int* __restrict__ list,
               int* __restrict__ cnt, int n)
{
    __shared__ int s[256];
    __shared__ int bofs;
    int t = threadIdx.x;
    int i = blockIdx.x * 256 + t;
    int f = (i < n) ? (int)flags[i] : 0;
    s[t] = f; __syncthreads();
    for (int off = 1; off < 256; off <<= 1) {
        int v = (t >= off) ? s[t - off] : 0;
        __syncthreads();
        s[t] += v;
        __syncthreads();
    }
    if (t == 255) bofs = atomicAdd(cnt, s[255]);
    __syncthreads();
    if (f) list[bofs + s[t] - 1] = i;
}

// ---------------------------------------------------------------------------
// Layer-0 pull, pair-packed, unroll-4 (8 gathers in flight per wave).
__global__ __launch_bounds__(256)
void k_pull0(const int* __restrict__ rowptr, const unsigned* __restrict__ packed,
             const float* __restrict__ comb, const u16* __restrict__ hb,
             u16* __restrict__ h0, int nNodes)
{
    __shared__ float sc[16];
    if (threadIdx.x < 16) sc[threadIdx.x] = comb[threadIdx.x];
    __syncthreads();
    int n = blockIdx.x * 4 + (threadIdx.x >> 6);
    if (n >= nNodes) return;
    const int lane = threadIdx.x & 63;
    const int half = lane >> 5;
    const int sub  = (lane >> 4) & 1;
    const int i2   = lane & 15;
    const long off = (long)sub * 32 + 2 * i2;
    int beg = rowptr[n], end = rowptr[n + 1];
    float a0 = 0.f, a1 = 0.f;
    int j = beg + half;
    // deep loop: 4 edges per half per iteration
    for (; j + 6 < end; j += 8) {
        unsigned pa = packed[j],     pb = packed[j + 2];
        unsigned pc = packed[j + 4], pd = packed[j + 6];
        unsigned va = *(const unsigned*)(hb + (long)(pa >> 3) * 64 + off);
        unsigned vb = *(const unsigned*)(hb + (long)(pb >> 3) * 64 + off);
        unsigned vc = *(const unsigned*)(hb + (long)(pc >> 3) * 64 + off);
        unsigned vd = *(const unsigned*)(hb + (long)(pd >> 3) * 64 + off);
        float ca = sc[(pa & 7) * 2 + sub];
        float cb = sc[(pb & 7) * 2 + sub];
        float cc = sc[(pc & 7) * 2 + sub];
        float cd = sc[(pd & 7) * 2 + sub];
        a0 = fmaf(ca, blo(va), a0);  a1 = fmaf(ca, bhi(va), a1);
        a0 = fmaf(cb, blo(vb), a0);  a1 = fmaf(cb, bhi(vb), a1);
        a0 = fmaf(cc, blo(vc), a0);  a1 = fmaf(cc, bhi(vc), a1);
        a0 = fmaf(cd, blo(vd), a0);  a1 = fmaf(cd, bhi(vd), a1);
    }
    for (; j + 2 < end; j += 4) {
        unsigned pa = packed[j], pb = packed[j + 2];
        unsigned va = *(const unsigned*)(hb + (long)(pa >> 3) * 64 + off);
        unsigned vb = *(const unsigned*)(hb + (long)(pb >> 3) * 64 + off);
        float ca = sc[(pa & 7) * 2 + sub];
        float cb = sc[(pb & 7) * 2 + sub];
        a0 = fmaf(ca, blo(va), a0);  a1 = fmaf(ca, bhi(va), a1);
        a0 = fmaf(cb, blo(vb), a0);  a1 = fmaf(cb, bhi(vb), a1);
    }
    if (j < end) {
        unsigned pa = packed[j];
        unsigned va = *(const unsigned*)(hb + (long)(pa >> 3) * 64 + off);
        float ca = sc[(pa & 7) * 2 + sub];
        a0 = fmaf(ca, blo(va), a0);  a1 = fmaf(ca, bhi(va), a1);
    }
    a0 += __shfl_xor(a0, 16);  a1 += __shfl_xor(a1, 16);
    a0 += __shfl_xor(a0, 32);  a1 += __shfl_xor(a1, 32);
    if (lane < 16) {
        unsigned* p = (unsigned*)(h0 + (long)n * 32 + 2 * i2);
        unsigned cur = *p;
        *p = bpack(tanhf(blo(cur) + a0), tanhf(bhi(cur) + a1));
    }
}

// ---------------------------------------------------------------------------
// Layer-1 pull (all nodes), pair-packed, unroll-4 (16 gathers in flight/wave).
__global__ __launch_bounds__(256)
void k_pull_u(const int* __restrict__ rowptr, const unsigned* __restrict__ packed,
              const float* __restrict__ comb, const u16* __restrict__ hsrc,
              u16* __restrict__ u, int nNodes)
{
    __shared__ float sc[16];
    if (threadIdx.x < 16) sc[threadIdx.x] = comb[threadIdx.x];
    __syncthreads();
    int n = blockIdx.x * 4 + (threadIdx.x >> 6);
    if (n >= nNodes) return;
    const int lane = threadIdx.x & 63;
    const int grp  = lane >> 4;
    const int i2   = lane & 15;
    int beg = rowptr[n], end = rowptr[n + 1];
    float u00 = 0.f, u01 = 0.f, u10 = 0.f, u11 = 0.f;
    int j = beg + grp;
    for (; j + 12 < end; j += 16) {
        unsigned pa = packed[j],     pb = packed[j + 4];
        unsigned pc = packed[j + 8], pd = packed[j + 12];
        unsigned va = *(const unsigned*)(hsrc + (long)(pa >> 3) * 32 + 2 * i2);
        unsigned vb = *(const unsigned*)(hsrc + (long)(pb >> 3) * 32 + 2 * i2);
        unsigned vc = *(const unsigned*)(hsrc + (long)(pc >> 3) * 32 + 2 * i2);
        unsigned vd = *(const unsigned*)(hsrc + (long)(pd >> 3) * 32 + 2 * i2);
        int ra = (pa & 7) * 2, rb = (pb & 7) * 2;
        int rc = (pc & 7) * 2, rd = (pd & 7) * 2;
        float alo = blo(va), ahi = bhi(va);
        float blo_ = blo(vb), bhi_ = bhi(vb);
        float clo = blo(vc), chi = bhi(vc);
        float dlo = blo(vd), dhi = bhi(vd);
        u00 = fmaf(sc[ra], alo, u00);      u01 = fmaf(sc[ra], ahi, u01);
        u10 = fmaf(sc[ra + 1], alo, u10);  u11 = fmaf(sc[ra + 1], ahi, u11);
        u00 = fmaf(sc[rb], blo_, u00);     u01 = fmaf(sc[rb], bhi_, u01);
        u10 = fmaf(sc[rb + 1], blo_, u10); u11 = fmaf(sc[rb + 1], bhi_, u11);
        u00 = fmaf(sc[rc], clo, u00);      u01 = fmaf(sc[rc], chi, u01);
        u10 = fmaf(sc[rc + 1], clo, u10);  u11 = fmaf(sc[rc + 1], chi, u11);
        u00 = fmaf(sc[rd], dlo, u00);      u01 = fmaf(sc[rd], dhi, u01);
        u10 = fmaf(sc[rd + 1], dlo, u10);  u11 = fmaf(sc[rd + 1], dhi, u11);
    }
    for (; j + 4 < end; j += 8) {
        unsigned pa = packed[j], pb = packed[j + 4];
        unsigned va = *(const unsigned*)(hsrc + (long)(pa >> 3) * 32 + 2 * i2);
        unsigned vb = *(const unsigned*)(hsrc + (long)(pb >> 3) * 32 + 2 * i2);
        int ra = (pa & 7) * 2, rb = (pb & 7) * 2;
        float alo = blo(va), ahi = bhi(va);
        float blo_ = blo(vb), bhi_ = bhi(vb);
        u00 = fmaf(sc[ra], alo, u00);      u01 = fmaf(sc[ra], ahi, u01);
        u10 = fmaf(sc[ra + 1], alo, u10);  u11 = fmaf(sc[ra + 1], ahi, u11);
        u00 = fmaf(sc[rb], blo_, u00);     u01 = fmaf(sc[rb], bhi_, u01);
        u10 = fmaf(sc[rb + 1], blo_, u10); u11 = fmaf(sc[rb + 1], bhi_, u11);
    }
    if (j < end) {
        unsigned pa = packed[j];
        unsigned va = *(const unsigned*)(hsrc + (long)(pa >> 3) * 32 + 2 * i2);
        int ra = (pa & 7) * 2;
        float alo = blo(va), ahi = bhi(va);
        u00 = fmaf(sc[ra], alo, u00);      u01 = fmaf(sc[ra], ahi, u01);
        u10 = fmaf(sc[ra + 1], alo, u10);  u11 = fmaf(sc[ra + 1], ahi, u11);
    }
    u00 += __shfl_xor(u00, 16);  u01 += __shfl_xor(u01, 16);
    u10 += __shfl_xor(u10, 16);  u11 += __shfl_xor(u11, 16);
    u00 += __shfl_xor(u00, 32);  u01 += __shfl_xor(u01, 32);
    u10 += __shfl_xor(u10, 32);  u11 += __shfl_xor(u11, 32);
    if (lane < 16) {
        unsigned* p0 = (unsigned*)(u + (long)n * 64 + 2 * i2);
        unsigned* p1 = (unsigned*)(u + (long)n * 64 + 32 + 2 * i2);
        *p0 = bpack(u00, u01);
        *p1 = bpack(u10, u11);
    }
}

// ---------------------------------------------------------------------------
// Layer-2 pull over REFERENCED nodes only (n = list[idx]), unroll-4.
__global__ __launch_bounds__(256)
void k_pull_uf(const int* __restrict__ rowptr, const unsigned* __restrict__ packed,
               const float* __restrict__ comb, const u16* __restrict__ hsrc,
               u16* __restrict__ u, const int* __restrict__ list,
               const int* __restrict__ cnt)
{
    __shared__ float sc[16];
    if (threadIdx.x < 16) sc[threadIdx.x] = comb[threadIdx.x];
    __syncthreads();
    const int count = *cnt;
    int idx = blockIdx.x * 4 + (threadIdx.x >> 6);
    if (idx >= count) return;
    const int n = list[idx];
    const int lane = threadIdx.x & 63;
    const int grp  = lane >> 4;
    const int i2   = lane & 15;
    int beg = rowptr[n], end = rowptr[n + 1];
    float u00 = 0.f, u01 = 0.f, u10 = 0.f, u11 = 0.f;
    int j = beg + grp;
    for (; j + 12 < end; j += 16) {
        unsigned pa = packed[j],     pb = packed[j + 4];
        unsigned pc = packed[j + 8], pd = packed[j + 12];
        unsigned va = *(const unsigned*)(hsrc + (long)(pa >> 3) * 32 + 2 * i2);
        unsigned vb = *(const unsigned*)(hsrc + (long)(pb >> 3) * 32 + 2 * i2);
        unsigned vc = *(const unsigned*)(hsrc + (long)(pc >> 3) * 32 + 2 * i2);
        unsigned vd = *(const unsigned*)(hsrc + (long)(pd >> 3) * 32 + 2 * i2);
        int ra = (pa & 7) * 2, rb = (pb & 7) * 2;
        int rc = (pc & 7) * 2, rd = (pd & 7) * 2;
        float alo = blo(va), ahi = bhi(va);
        float blo_ = blo(vb), bhi_ = bhi(vb);
        float clo = blo(vc), chi = bhi(vc);
        float dlo = blo(vd), dhi = bhi(vd);
        u00 = fmaf(sc[ra], alo, u00);      u01 = fmaf(sc[ra], ahi, u01);
        u10 = fmaf(sc[ra + 1], alo, u10);  u11 = fmaf(sc[ra + 1], ahi, u11);
        u00 = fmaf(sc[rb], blo_, u00);     u01 = fmaf(sc[rb], bhi_, u01);
        u10 = fmaf(sc[rb + 1], blo_, u10); u11 = fmaf(sc[rb + 1], bhi_, u11);
        u00 = fmaf(sc[rc], clo, u00);      u01 = fmaf(sc[rc], chi, u01);
        u10 = fmaf(sc[rc + 1], clo, u10);  u11 = fmaf(sc[rc + 1], chi, u11);
        u00 = fmaf(sc[rd], dlo, u00);      u01 = fmaf(sc[rd], dhi, u01);
        u10 = fmaf(sc[rd + 1], dlo, u10);  u11 = fmaf(sc[rd + 1], dhi, u11);
    }
    for (; j + 4 < end; j += 8) {
        unsigned pa = packed[j], pb = packed[j + 4];
        unsigned va = *(const unsigned*)(hsrc + (long)(pa >> 3) * 32 + 2 * i2);
        unsigned vb = *(const unsigned*)(hsrc + (long)(pb >> 3) * 32 + 2 * i2);
        int ra = (pa & 7) * 2, rb = (pb & 7) * 2;
        float alo = blo(va), ahi = bhi(va);
        float blo_ = blo(vb), bhi_ = bhi(vb);
        u00 = fmaf(sc[ra], alo, u00);      u01 = fmaf(sc[ra], ahi, u01);
        u10 = fmaf(sc[ra + 1], alo, u10);  u11 = fmaf(sc[ra + 1], ahi, u11);
        u00 = fmaf(sc[rb], blo_, u00);     u01 = fmaf(sc[rb], bhi_, u01);
        u10 = fmaf(sc[rb + 1], blo_, u10); u11 = fmaf(sc[rb + 1], bhi_, u11);
    }
    if (j < end) {
        unsigned pa = packed[j];
        unsigned va = *(const unsigned*)(hsrc + (long)(pa >> 3) * 32 + 2 * i2);
        int ra = (pa & 7) * 2;
        float alo = blo(va), ahi = bhi(va);
        u00 = fmaf(sc[ra], alo, u00);      u01 = fmaf(sc[ra], ahi, u01);
        u10 = fmaf(sc[ra + 1], alo, u10);  u11 = fmaf(sc[ra + 1], ahi, u11);
    }
    u00 += __shfl_xor(u00, 16);  u01 += __shfl_xor(u01, 16);
    u10 += __shfl_xor(u10, 16);  u11 += __shfl_xor(u11, 16);
    u00 += __shfl_xor(u00, 32);  u01 += __shfl_xor(u01, 32);
    u10 += __shfl_xor(u10, 32);  u11 += __shfl_xor(u11, 32);
    if (lane < 16) {
        unsigned* p0 = (unsigned*)(u + (long)n * 64 + 2 * i2);
        unsigned* p1 = (unsigned*)(u + (long)n * 64 + 32 + 2 * i2);
        *p0 = bpack(u00, u01);
        *p1 = bpack(u10, u11);
    }
}

// ---------------------------------------------------------------------------
// Post GEMM for layer 1 (all nodes — round-11 version).
__global__ __launch_bounds__(256, 2)
void k_post(const u16* __restrict__ u, const u16* __restrict__ hsrc,
            const float* __restrict__ V, const float* __restrict__ loopw,
            const float* __restrict__ bias, u16* __restrict__ hdst, int nNodes)
{
    __shared__ float CW[96 * 32];
    for (int idx = threadIdx.x; idx < 96 * 32; idx += 256) {
        int i = idx / 32, o = idx % 32;
        CW[idx] = (i < 64) ? V[i * 32 + o]
                           : loopw[(i - 64) * 32 + o];
    }
    __syncthreads();

    const int cg = threadIdx.x & 7;
    const int ng = threadIdx.x >> 3;
    const int c0 = cg * 4;
    const int base = blockIdx.x * 128 + ng * 4;
    if (base >= nNodes) return;

    long rows[4];
    #pragma unroll
    for (int j = 0; j < 4; ++j)
        rows[j] = (long)min(base + j, nNodes - 1);

    float acc[4][4] = {};
    #pragma unroll 2
    for (int i = 0; i < 96; i += 4) {
        f4 w0 = *(const f4*)&CW[(i + 0) * 32 + c0];
        f4 w1 = *(const f4*)&CW[(i + 1) * 32 + c0];
        f4 w2 = *(const f4*)&CW[(i + 2) * 32 + c0];
        f4 w3 = *(const f4*)&CW[(i + 3) * 32 + c0];
        #pragma unroll
        for (int j = 0; j < 4; ++j) {
            f4 hv;
            if (i < 64) hv = b4f(*(const us4*)(u + rows[j] * 64 + i));
            else        hv = b4f(*(const us4*)(hsrc + rows[j] * 32 + (i - 64)));
            #pragma unroll
            for (int q = 0; q < 4; ++q)
                acc[j][q] = fmaf(hv[3], w3[q],
                            fmaf(hv[2], w2[q],
                            fmaf(hv[1], w1[q],
                            fmaf(hv[0], w0[q], acc[j][q]))));
        }
    }

    f4 bv = *(const f4*)(bias + c0);
    #pragma unroll
    for (int j = 0; j < 4; ++j)
        if (base + j < nNodes) {
            us4 v = {f2b(tanhf(acc[j][0] + bv[0])), f2b(tanhf(acc[j][1] + bv[1])),
                     f2b(tanhf(acc[j][2] + bv[2])), f2b(tanhf(acc[j][3] + bv[3]))};
            *(us4*)(hdst + (long)(base + j) * 32 + c0) = v;
        }
}

// ---------------------------------------------------------------------------
// Post GEMM for layer 2 over REFERENCED nodes only.
__global__ __launch_bounds__(256, 2)
void k_postf(const u16* __restrict__ u, const u16* __restrict__ hsrc,
             const float* __restrict__ V, const float* __restrict__ loopw,
             const float* __restrict__ bias, u16* __restrict__ hdst,
             const int* __restrict__ list, const int* __restrict__ cnt)
{
    __shared__ float CW[96 * 32];
    for (int idx = threadIdx.x; idx < 96 * 32; idx += 256) {
        int i = idx / 32, o = idx % 32;
        CW[idx] = (i < 64) ? V[i * 32 + o]
                           : loopw[(i - 64) * 32 + o];
    }
    __syncthreads();

    const int count = *cnt;
    const int cg = threadIdx.x & 7;
    const int ng = threadIdx.x >> 3;
    const int c0 = cg * 4;
    const int base = blockIdx.x * 128 + ng * 4;
    if (base >= count) return;

    long rows[4];
    #pragma unroll
    for (int j = 0; j < 4; ++j)
        rows[j] = (long)list[min(base + j, count - 1)];

    float acc[4][4] = {};
    #pragma unroll 2
    for (int i = 0; i < 96; i += 4) {
        f4 w0 = *(const f4*)&CW[(i + 0) * 32 + c0];
        f4 w1 = *(const f4*)&CW[(i + 1) * 32 + c0];
        f4 w2 = *(const f4*)&CW[(i + 2) * 32 + c0];
        f4 w3 = *(const f4*)&CW[(i + 3) * 32 + c0];
        #pragma unroll
        for (int j = 0; j < 4; ++j) {
            f4 hv;
            if (i < 64) hv = b4f(*(const us4*)(u + rows[j] * 64 + i));
            else        hv = b4f(*(const us4*)(hsrc + rows[j] * 32 + (i - 64)));
            #pragma unroll
            for (int q = 0; q < 4; ++q)
                acc[j][q] = fmaf(hv[3], w3[q],
                            fmaf(hv[2], w2[q],
                            fmaf(hv[1], w1[q],
                            fmaf(hv[0], w0[q], acc[j][q]))));
        }
    }

    f4 bv = *(const f4*)(bias + c0);
    #pragma unroll
    for (int j = 0; j < 4; ++j)
        if (base + j < count) {
            us4 v = {f2b(tanhf(acc[j][0] + bv[0])), f2b(tanhf(acc[j][1] + bv[1])),
                     f2b(tanhf(acc[j][2] + bv[2])), f2b(tanhf(acc[j][3] + bv[3]))};
            *(us4*)(hdst + rows[j] * 32 + c0) = v;
        }
}

// ---------------------------------------------------------------------------
// Fused MLP heads + reparameterization over the COMPACTED node list only.
__global__ __launch_bounds__(256, 2)
void k_mlp(const u16* __restrict__ h0, const u16* __restrict__ h1,
           const u16* __restrict__ h2,
           const float* __restrict__ Wm1, const float* __restrict__ bm1,
           const float* __restrict__ Wm2, const float* __restrict__ bm2,
           const float* __restrict__ Ws1, const float* __restrict__ bs1,
           const float* __restrict__ Ws2, const float* __restrict__ bs2,
           const float* __restrict__ noise, float* __restrict__ z,
           const int* __restrict__ list, const int* __restrict__ cnt)
{
    const int count = *cnt;
    const int base = blockIdx.x * 64;
    if (base >= count) return;

    __shared__ float sW1[2][96 * 32];
    __shared__ float sW2[2][32 * 128];
    __shared__ float sb1[2][32];
    __shared__ float sb2[2][128];
    __shared__ float shid[2][64][32];

    for (int i = threadIdx.x; i < 96 * 32; i += 256) { sW1[0][i] = Wm1[i]; sW1[1][i] = Ws1[i]; }
    for (int i = threadIdx.x; i < 32 * 128; i += 256) { sW2[0][i] = Wm2[i]; sW2[1][i] = Ws2[i]; }
    if (threadIdx.x < 32)  { sb1[0][threadIdx.x] = bm1[threadIdx.x]; sb1[1][threadIdx.x] = bs1[threadIdx.x]; }
    if (threadIdx.x < 128) { sb2[0][threadIdx.x] = bm2[threadIdx.x]; sb2[1][threadIdx.x] = bs2[threadIdx.x]; }
    __syncthreads();

    // ---- phase A: hidden = relu(cs @ W1 + b1) ----
    {
        const int head = threadIdx.x >> 7;
        const int rem  = threadIdx.x & 127;
        const int ng   = rem >> 3;
        const int c0   = (rem & 7) * 4;
        const float* sW = sW1[head];
        long rows[4];
        #pragma unroll
        for (int j = 0; j < 4; ++j)
            rows[j] = (long)list[min(base + ng * 4 + j, count - 1)];

        float acc[4][4] = {};
        const u16* hs[3] = {h0, h1, h2};
        #pragma unroll
        for (int part = 0; part < 3; ++part) {
            const u16* hp = hs[part];
            #pragma unroll
            for (int kk = 0; kk < 32; kk += 4) {
                const int k = part * 32 + kk;
                f4 w0 = *(const f4*)&sW[(k + 0) * 32 + c0];
                f4 w1 = *(const f4*)&sW[(k + 1) * 32 + c0];
                f4 w2 = *(const f4*)&sW[(k + 2) * 32 + c0];
                f4 w3 = *(const f4*)&sW[(k + 3) * 32 + c0];
                #pragma unroll
                for (int j = 0; j < 4; ++j) {
                    f4 hv = b4f(*(const us4*)(hp + rows[j] * 32 + kk));
                    #pragma unroll
                    for (int q = 0; q < 4; ++q)
                        acc[j][q] = fmaf(hv[3], w3[q],
                                    fmaf(hv[2], w2[q],
                                    fmaf(hv[1], w1[q],
                                    fmaf(hv[0], w0[q], acc[j][q]))));
                }
            }
        }
        f4 bv = *(const f4*)&sb1[head][c0];
        #pragma unroll
        for (int j = 0; j < 4; ++j) {
            f4 v = {fmaxf(acc[j][0] + bv[0], 0.f), fmaxf(acc[j][1] + bv[1], 0.f),
                    fmaxf(acc[j][2] + bv[2], 0.f), fmaxf(acc[j][3] + bv[3], 0.f)};
            *(f4*)&shid[head][ng * 4 + j][c0] = v;
        }
    }
    __syncthreads();

    // ---- phase B: out = hid @ W2 + b2; z = mean + noise * exp(log_std) ----
    const int ng = threadIdx.x >> 5;
    const int c0 = (threadIdx.x & 31) * 4;
    #pragma unroll
    for (int pass = 0; pass < 2; ++pass) {
        const int nb = pass * 32 + ng * 4;
        float am[4][4] = {}, as_[4][4] = {};
        #pragma unroll 4
        for (int k = 0; k < 32; k += 4) {
            f4 wm0 = *(const f4*)&sW2[0][(k + 0) * 128 + c0];
            f4 wm1 = *(const f4*)&sW2[0][(k + 1) * 128 + c0];
            f4 wm2 = *(const f4*)&sW2[0][(k + 2) * 128 + c0];
            f4 wm3 = *(const f4*)&sW2[0][(k + 3) * 128 + c0];
            f4 ws0 = *(const f4*)&sW2[1][(k + 0) * 128 + c0];
            f4 ws1 = *(const f4*)&sW2[1][(k + 1) * 128 + c0];
            f4 ws2 = *(const f4*)&sW2[1][(k + 2) * 128 + c0];
            f4 ws3 = *(const f4*)&sW2[1][(k + 3) * 128 + c0];
            #pragma unroll
            for (int j = 0; j < 4; ++j) {
                f4 hm = *(const f4*)&shid[0][nb + j][k];
                f4 hv = *(const f4*)&shid[1][nb + j][k];
                #pragma unroll
                for (int q = 0; q < 4; ++q) {
                    am[j][q]  = fmaf(hm[3], wm3[q],
                                fmaf(hm[2], wm2[q],
                                fmaf(hm[1], wm1[q],
                                fmaf(hm[0], wm0[q], am[j][q]))));
                    as_[j][q] = fmaf(hv[3], ws3[q],
                                fmaf(hv[2], ws2[q],
                                fmaf(hv[1], ws1[q],
                                fmaf(hv[0], ws0[q], as_[j][q]))));
                }
            }
        }
        f4 b2m = *(const f4*)&sb2[0][c0];
        f4 b2s = *(const f4*)&sb2[1][c0];
        #pragma unroll
        for (int j = 0; j < 4; ++j) {
            const int idx = base + nb + j;
            if (idx < count) {
                const long n = (long)list[idx];
                f4 nz = *(const f4*)(noise + n * 128 + c0);
                f4 v;
                #pragma unroll
                for (int q = 0; q < 4; ++q)
                    v[q] = fmaf(nz[q], expf(as_[j][q] + b2s[q]), am[j][q] + b2m[q]);
                *(f4*)(z + n * 128 + c0) = v;
            }
        }
    }
}

// ---------------------------------------------------------------------------
__global__ __launch_bounds__(256)
void k_pairs(const float* __restrict__ z, const int* __restrict__ ui,
             const int* __restrict__ ii, float* __restrict__ out, int U, int T)
{
    int w = (blockIdx.x * 256 + threadIdx.x) >> 6;
    int lane = threadIdx.x & 63;
    if (w >= U) return;
    int a = ui[w], b = ii[w];
    float a0 = z[(long)a * 128 + lane], a1 = z[(long)a * 128 + 64 + lane];
    float b0 = z[(long)b * 128 + lane], b1 = z[(long)b * 128 + 64 + lane];
    float* res = out + U + T;
    res[(long)w * 128 + lane] = a0;
    res[(long)w * 128 + 64 + lane] = a1;
    res[(long)(U + w) * 128 + lane] = b0;
    res[(long)(U + w) * 128 + 64 + lane] = b1;
    float d = fmaf(a0, b0, a1 * b1);
    #pragma unroll
    for (int off = 32; off; off >>= 1) d += __shfl_xor(d, off);
    if (lane == 0) out[w] = d;
}

__global__ __launch_bounds__(256)
void k_preds(const float* __restrict__ z, const int* __restrict__ ts,
             const int* __restrict__ td, float* __restrict__ out, int U, int T)
{
    int w = (blockIdx.x * 256 + threadIdx.x) >> 6;
    int lane = threadIdx.x & 63;
    if (w >= T) return;
    int a = ts[w], b = td[w];
    float a0 = z[(long)a * 128 + lane], a1 = z[(long)a * 128 + 64 + lane];
    float b0 = z[(long)b * 128 + lane], b1 = z[(long)b * 128 + 64 + lane];
    float d = fmaf(a0, b0, a1 * b1);
    #pragma unroll
    for (int off = 32; off; off >>= 1) d += __shfl_xor(d, off);
    if (lane == 0) out[U + w] = d;
}

// ---------------------------------------------------------------------------
extern "C" void kernel_launch(void* const* d_in, const int* in_sizes, int n_in,
                              void* d_out, int out_size, void* d_ws, size_t ws_size,
                              hipStream_t stream)
{
    const float* x     = (const float*)d_in[0];
    const int*   src   = (const int*)d_in[1];
    const int*   dst   = (const int*)d_in[2];
    const int*   et    = (const int*)d_in[3];
    const float* noise = (const float*)d_in[4];
    const int*   ui    = (const int*)d_in[5];
    const int*   ii    = (const int*)d_in[6];
    const int*   tes   = (const int*)d_in[7];
    const int*   ted   = (const int*)d_in[8];
    const float* V0    = (const float*)d_in[9];
    const float* comb0 = (const float*)d_in[10];
    const float* loop0 = (const float*)d_in[11];
    const float* b0    = (const float*)d_in[12];
    const float* V1    = (const float*)d_in[13];
    const float* comb1 = (const float*)d_in[14];
    const float* loop1 = (const float*)d_in[15];
    const float* b1    = (const float*)d_in[16];
    const float* V2    = (const float*)d_in[17];
    const float* comb2 = (const float*)d_in[18];
    const float* loop2 = (const float*)d_in[19];
    const float* b2    = (const float*)d_in[20];
    const float* Wm1   = (const float*)d_in[21];
    const float* bm1   = (const float*)d_in[22];
    const float* Wm2   = (const float*)d_in[23];
    const float* bm2   = (const float*)d_in[24];
    const float* Ws1   = (const float*)d_in[25];
    const float* bs1   = (const float*)d_in[26];
    const float* Ws2   = (const float*)d_in[27];
    const float* bs2   = (const float*)d_in[28];

    const int N = in_sizes[0] / 128;   // 200000
    const int E = in_sizes[1];         // 3200000
    const int U = in_sizes[5];
    const int T = in_sizes[7];
    const int NB = (N + 255) / 256;    // 782 buckets
    const int chunk = (E + NBLK - 1) / NBLK;

    float* out = (float*)d_out;

    // Workspace layout (bytes):
    //  hb  bf16 [N][64] | h0/h1/h2 bf16 [N][32] | u bf16 [N][64]
    //  z f32 [N][128]  (CSR int scratch aliases z; dead by k_mlp)
    //  flags char[N] | list int[N] | cnt int
    char* W = (char*)d_ws;
    u16*   hb = (u16*)W;
    u16*   h0 = (u16*)(W + (size_t)N * 64 * 2);
    u16*   h1 = h0 + (size_t)N * 32;
    u16*   h2 = h1 + (size_t)N * 32;
    u16*   u  = (u16*)(W + (size_t)N * 64 * 2 + (size_t)N * 32 * 2 * 3);
    float* z  = (float*)(u + (size_t)N * 64);
    unsigned char* flags = (unsigned char*)(z + (size_t)N * 128);
    int*   list = (int*)(flags + (size_t)N);
    int*   cnt  = list + N;

    int*      rowptr = (int*)z;
    unsigned* packed = (unsigned*)(rowptr + N + 1);
    unsigned* bpk    = packed + E;
    int*      hist   = (int*)(bpk + E);
    int*      basep  = hist + NBLK * MAXB;
    int*      colsum = basep + NBLK * MAXB;
    int*      bb     = colsum + NB;

    const int hbBlocks   = (N + 63) / 64;
    const int pullBlocks = (N + 3) / 4;
    const int postBlocks = (N + 127) / 128;
    const int mlpBlocks  = (N + 63) / 64;

    // ---- referenced-node flags + compaction ----
    k_zerof<<<(N / 4 + 255) / 256, 256, 0, stream>>>((int*)flags, N / 4, cnt);
    k_flags<<<(2 * U + 2 * T + 255) / 256, 256, 0, stream>>>(ui, ii, tes, ted, U, T, flags);
    k_compact<<<NB, 256, 0, stream>>>(flags, list, cnt, N);

    // ---- contention-free bucketed CSR build (by dst) ----
    k_bhist2<<<NBLK, 256, 0, stream>>>(dst, hist, E, NB, chunk);
    k_colscan<<<NB, 256, 0, stream>>>(hist, basep, colsum, NB);
    k_bscan2<<<1, 1024, 0, stream>>>(colsum, bb, rowptr, NB, N, E);
    k_bscatter2<<<NBLK, 256, 0, stream>>>(src, dst, et, basep, bb, bpk, E, NB, chunk);
    k_bucket<<<NB, 256, 0, stream>>>(bpk, bb, rowptr, packed, N);

    // ---- layer 0 (MFMA GEMM + pull) ----
    k_hb<<<hbBlocks, 256, 0, stream>>>(x, V0, loop0, b0, hb, h0, N);
    k_pull0<<<pullBlocks, 256, 0, stream>>>(rowptr, packed, comb0, hb, h0, N);

    // ---- layer 1 (all nodes) ----
    k_pull_u<<<pullBlocks, 256, 0, stream>>>(rowptr, packed, comb1, h0, u, N);
    k_post<<<postBlocks, 256, 0, stream>>>(u, h0, V1, loop1, b1, h1, N);

    // ---- layer 2 (referenced nodes only) ----
    k_pull_uf<<<pullBlocks, 256, 0, stream>>>(rowptr, packed, comb2, h1, u, list, cnt);
    k_postf<<<postBlocks, 256, 0, stream>>>(u, h1, V2, loop2, b2, h2, list, cnt);

    // ---- heads + reparameterization (compacted) ----
    k_mlp<<<mlpBlocks, 256, 0, stream>>>(h0, h1, h2, Wm1, bm1, Wm2, bm2,
                                         Ws1, bs1, Ws2, bs2, noise, z, list, cnt);
    // ---- outputs ----
    k_pairs<<<(U * 64 + 255) / 256, 256, 0, stream>>>(z, ui, ii, out, U, T);
    k_preds<<<(T * 64 + 255) / 256, 256, 0, stream>>>(z, tes, ted, out, U, T);
}

// Round 15
// 579.620 us; speedup vs baseline: 6.4667x; 1.0176x over previous
//
#include <hip/hip_runtime.h>
#include <hip/hip_bf16.h>

// N=200000, E=3200000, R=8, B=2, IN=128, H=32, OUT=128, U=10000, T=50000.

typedef float f4 __attribute__((ext_vector_type(4)));
typedef short s8 __attribute__((ext_vector_type(8)));   // 8 bf16 = 4 VGPRs (MFMA frag)
typedef unsigned short u16;
typedef u16 us4 __attribute__((ext_vector_type(4)));   // 4 bf16 = 8 bytes

__device__ inline u16 f2b(float f) {
    __hip_bfloat16 h = __float2bfloat16(f);
    return __builtin_bit_cast(u16, h);
}
__device__ inline float b2f(u16 s) {
    return __bfloat162float(__builtin_bit_cast(__hip_bfloat16, s));
}
__device__ inline f4 b4f(us4 v) {
    f4 r = {b2f(v.x), b2f(v.y), b2f(v.z), b2f(v.w)};
    return r;
}
__device__ inline float blo(unsigned v) { return b2f((u16)(v & 0xffffu)); }
__device__ inline float bhi(unsigned v) { return b2f((u16)(v >> 16)); }
__device__ inline unsigned bpack(float a, float b) {
    return (unsigned)f2b(a) | ((unsigned)f2b(b) << 16);
}

#define NBLK 256      // scatter blocks
#define MAXB 800      // >= NB = ceil(N/256) = 782
#define PADK 136      // 128 + 8 bf16 pad (k_hb LDS)

// ---------------------------------------------------------------------------
// Layer-0 basis+selfloop GEMM on MFMA (round-11 version, verified).
__global__ __launch_bounds__(256, 3)
void k_hb(const float* __restrict__ x, const float* __restrict__ V,
          const float* __restrict__ loopw, const float* __restrict__ bias,
          u16* __restrict__ hb, u16* __restrict__ agg, int nNodes)
{
    __shared__ u16 XA[64 * PADK];
    __shared__ u16 WB[96 * PADK];
    __shared__ float sbias[32];

    const int t = threadIdx.x;
    const int base = blockIdx.x * 64;

    if (t < 32) sbias[t] = bias[t];
    for (int i = t; i < 3072; i += 256) {
        if (i < 2048) {
            f4 v = *(const f4*)(V + (long)i * 4);
            int b = i >> 10, k = (i >> 3) & 127, o0 = (i & 7) * 4;
            int col = b * 32 + o0;
            #pragma unroll
            for (int s = 0; s < 4; ++s) WB[(col + s) * PADK + k] = f2b(v[s]);
        } else {
            int j = i - 2048;
            f4 v = *(const f4*)(loopw + (long)j * 4);
            int k = j >> 3, o0 = (j & 7) * 4;
            int col = 64 + o0;
            #pragma unroll
            for (int s = 0; s < 4; ++s) WB[(col + s) * PADK + k] = f2b(v[s]);
        }
    }
    for (int i = t; i < 2048; i += 256) {
        int row = i >> 5, c4 = i & 31;
        long gr = (long)min(base + row, nNodes - 1);
        f4 xv = *(const f4*)(x + gr * 128 + (long)c4 * 4);
        us4 v = {f2b(xv[0]), f2b(xv[1]), f2b(xv[2]), f2b(xv[3])};
        *(us4*)&XA[row * PADK + c4 * 4] = v;
    }
    __syncthreads();

    const int w    = t >> 6;
    const int l    = t & 63;
    const int rsel = l & 15;
    const int kg   = l >> 4;

    f4 acc[6] = {};
    for (int ks = 0; ks < 4; ++ks) {
        s8 a = *(const s8*)&XA[(w * 16 + rsel) * PADK + ks * 32 + kg * 8];
        #pragma unroll
        for (int ct = 0; ct < 6; ++ct) {
            s8 b = *(const s8*)&WB[(ct * 16 + rsel) * PADK + ks * 32 + kg * 8];
            acc[ct] = __builtin_amdgcn_mfma_f32_16x16x32_bf16(a, b, acc[ct], 0, 0, 0);
        }
    }

    #pragma unroll
    for (int ct = 0; ct < 6; ++ct) {
        int col = ct * 16 + rsel;
        #pragma unroll
        for (int r = 0; r < 4; ++r) {
            int node = base + w * 16 + kg * 4 + r;
            if (node < nNodes) {
                float v = acc[ct][r];
                if (col < 64) hb[(long)node * 64 + col] = f2b(v);
                else          agg[(long)node * 32 + (col - 64)] = f2b(v + sbias[col - 64]);
            }
        }
    }
}

// ---------------------------------------------------------------------------
// Contention-free bucketed CSR build (round-11 version).
__global__ __launch_bounds__(256)
void k_bhist2(const int* __restrict__ dst, int* __restrict__ hist,
              int nEdges, int nB, int chunk)
{
    __shared__ int hloc[MAXB];
    for (int i = threadIdx.x; i < nB; i += 256) hloc[i] = 0;
    __syncthreads();
    const int ebeg = blockIdx.x * chunk;
    const int eend = min(ebeg + chunk, nEdges);
    for (int e = ebeg + threadIdx.x; e < eend; e += 256)
        atomicAdd(&hloc[dst[e] >> 8], 1);
    __syncthreads();
    for (int i = threadIdx.x; i < nB; i += 256)
        hist[blockIdx.x * MAXB + i] = hloc[i];
}

__global__ __launch_bounds__(256)
void k_colscan(const int* __restrict__ hist, int* __restrict__ base,
               int* __restrict__ colsum, int nB)
{
    __shared__ int s[256];
    const int b = blockIdx.x;
    const int t = threadIdx.x;
    int v = hist[t * MAXB + b];
    s[t] = v; __syncthreads();
    for (int off = 1; off < 256; off <<= 1) {
        int tmp = (t >= off) ? s[t - off] : 0;
        __syncthreads();
        s[t] += tmp;
        __syncthreads();
    }
    base[t * MAXB + b] = s[t] - v;
    if (t == 255) colsum[b] = s[255];
}

__global__ __launch_bounds__(1024)
void k_bscan2(const int* __restrict__ colsum, int* __restrict__ bb,
              int* __restrict__ rowptr, int nB, int nNodes, int nEdges)
{
    __shared__ int s[1024];
    int t = threadIdx.x;
    int v = (t < nB) ? colsum[t] : 0;
    s[t] = v; __syncthreads();
    for (int off = 1; off < 1024; off <<= 1) {
        int tmp = (t >= off) ? s[t - off] : 0;
        __syncthreads();
        s[t] += tmp;
        __syncthreads();
    }
    if (t < nB) bb[t] = s[t] - v;
    if (t == 0) { bb[nB] = nEdges; rowptr[nNodes] = nEdges; }
}

__global__ __launch_bounds__(256)
void k_bscatter2(const int* __restrict__ src, const int* __restrict__ dst,
                 const int* __restrict__ et, const int* __restrict__ base,
                 const int* __restrict__ bb, unsigned* __restrict__ bpk,
                 int nEdges, int nB, int chunk)
{
    __shared__ int sbase[MAXB];
    __shared__ int cur[MAXB];
    for (int i = threadIdx.x; i < nB; i += 256) {
        sbase[i] = bb[i] + base[blockIdx.x * MAXB + i];
        cur[i] = 0;
    }
    __syncthreads();
    const int ebeg = blockIdx.x * chunk;
    const int eend = min(ebeg + chunk, nEdges);
    for (int e = ebeg + threadIdx.x; e < eend; e += 256) {
        int d = dst[e];
        int b = d >> 8;
        int r = atomicAdd(&cur[b], 1);
        bpk[sbase[b] + r] = ((unsigned)(d & 255) << 21)
                          | ((unsigned)src[e] << 3) | (unsigned)et[e];
    }
}

__global__ __launch_bounds__(256)
void k_bucket(const unsigned* __restrict__ bpk, const int* __restrict__ bbase,
              int* __restrict__ rowptr, unsigned* __restrict__ packed, int nNodes)
{
    __shared__ int s[256];
    __shared__ int cur[256];
    const int b = blockIdx.x;
    const int t = threadIdx.x;
    const int ebeg = bbase[b], eend = bbase[b + 1];

    cur[t] = 0;
    __syncthreads();
    for (int j = ebeg + t; j < eend; j += 256)
        atomicAdd(&cur[bpk[j] >> 21], 1);
    __syncthreads();
    int v = cur[t];
    s[t] = v; __syncthreads();
    for (int off = 1; off < 256; off <<= 1) {
        int tmp = (t >= off) ? s[t - off] : 0;
        __syncthreads();
        s[t] += tmp;
        __syncthreads();
    }
    int ex = s[t] - v;
    int node = b * 256 + t;
    if (node < nNodes) rowptr[node] = ebeg + ex;
    cur[t] = ex;
    __syncthreads();
    for (int j = ebeg + t; j < eend; j += 256) {
        unsigned p = bpk[j];
        int pos = ebeg + atomicAdd(&cur[p >> 21], 1);
        packed[pos] = p & 0x1FFFFFu;
    }
}

// ---------------------------------------------------------------------------
// Referenced-node set: flags + compaction.
__global__ __launch_bounds__(256)
void k_zerof(int* __restrict__ flags4, int n4, int* __restrict__ cnt)
{
    int i = blockIdx.x * 256 + threadIdx.x;
    if (i < n4) flags4[i] = 0;
    if (i == 0) *cnt = 0;
}

__global__ __launch_bounds__(256)
void k_flags(const int* __restrict__ ui, const int* __restrict__ ii,
             const int* __restrict__ tes, const int* __restrict__ ted,
             int U, int T, unsigned char* __restrict__ flags)
{
    int g = blockIdx.x * 256 + threadIdx.x;
    int idx;
    if (g < U)               idx = ui[g];
    else if (g < 2 * U)      idx = ii[g - U];
    else if (g < 2 * U + T)  idx = tes[g - 2 * U];
    else if (g < 2 * U + 2 * T) idx = ted[g - 2 * U - T];
    else return;
    flags[idx] = 1;
}

__global__ __launch_bounds__(256)
void k_compact(const unsigned char* __restrict__ flags, int* __restrict__ list,
               int* __restrict__ cnt, int n)
{
    __shared__ int s[256];
    __shared__ int bofs;
    int t = threadIdx.x;
    int i = blockIdx.x * 256 + t;
    int f = (i < n) ? (int)flags[i] : 0;
    s[t] = f; __syncthreads();
    for (int off = 1; off < 256; off <<= 1) {
        int v = (t >= off) ? s[t - off] : 0;
        __syncthreads();
        s[t] += v;
        __syncthreads();
    }
    if (t == 255) bofs = atomicAdd(cnt, s[255]);
    __syncthreads();
    if (f) list[bofs + s[t] - 1] = i;
}

// ---------------------------------------------------------------------------
// Layer-0 pull, pair-packed, unroll-8 (16 gathers in flight per wave).
__global__ __launch_bounds__(256)
void k_pull0(const int* __restrict__ rowptr, const unsigned* __restrict__ packed,
             const float* __restrict__ comb, const u16* __restrict__ hb,
             u16* __restrict__ h0, int nNodes)
{
    __shared__ float sc[16];
    if (threadIdx.x < 16) sc[threadIdx.x] = comb[threadIdx.x];
    __syncthreads();
    int n = blockIdx.x * 4 + (threadIdx.x >> 6);
    if (n >= nNodes) return;
    const int lane = threadIdx.x & 63;
    const int half = lane >> 5;
    const int sub  = (lane >> 4) & 1;
    const int i2   = lane & 15;
    const long off = (long)sub * 32 + 2 * i2;
    int beg = rowptr[n], end = rowptr[n + 1];
    float a0 = 0.f, a1 = 0.f;
    int j = beg + half;
    // unroll-8: 8 edges per half per iteration
    for (; j + 14 < end; j += 16) {
        unsigned p[8], v[8];
        #pragma unroll
        for (int q = 0; q < 8; ++q) p[q] = packed[j + 2 * q];
        #pragma unroll
        for (int q = 0; q < 8; ++q)
            v[q] = *(const unsigned*)(hb + (long)(p[q] >> 3) * 64 + off);
        #pragma unroll
        for (int q = 0; q < 8; ++q) {
            float c = sc[(p[q] & 7) * 2 + sub];
            a0 = fmaf(c, blo(v[q]), a0);  a1 = fmaf(c, bhi(v[q]), a1);
        }
    }
    for (; j + 6 < end; j += 8) {
        unsigned pa = packed[j],     pb = packed[j + 2];
        unsigned pc = packed[j + 4], pd = packed[j + 6];
        unsigned va = *(const unsigned*)(hb + (long)(pa >> 3) * 64 + off);
        unsigned vb = *(const unsigned*)(hb + (long)(pb >> 3) * 64 + off);
        unsigned vc = *(const unsigned*)(hb + (long)(pc >> 3) * 64 + off);
        unsigned vd = *(const unsigned*)(hb + (long)(pd >> 3) * 64 + off);
        float ca = sc[(pa & 7) * 2 + sub];
        float cb = sc[(pb & 7) * 2 + sub];
        float cc = sc[(pc & 7) * 2 + sub];
        float cd = sc[(pd & 7) * 2 + sub];
        a0 = fmaf(ca, blo(va), a0);  a1 = fmaf(ca, bhi(va), a1);
        a0 = fmaf(cb, blo(vb), a0);  a1 = fmaf(cb, bhi(vb), a1);
        a0 = fmaf(cc, blo(vc), a0);  a1 = fmaf(cc, bhi(vc), a1);
        a0 = fmaf(cd, blo(vd), a0);  a1 = fmaf(cd, bhi(vd), a1);
    }
    for (; j + 2 < end; j += 4) {
        unsigned pa = packed[j], pb = packed[j + 2];
        unsigned va = *(const unsigned*)(hb + (long)(pa >> 3) * 64 + off);
        unsigned vb = *(const unsigned*)(hb + (long)(pb >> 3) * 64 + off);
        float ca = sc[(pa & 7) * 2 + sub];
        float cb = sc[(pb & 7) * 2 + sub];
        a0 = fmaf(ca, blo(va), a0);  a1 = fmaf(ca, bhi(va), a1);
        a0 = fmaf(cb, blo(vb), a0);  a1 = fmaf(cb, bhi(vb), a1);
    }
    if (j < end) {
        unsigned pa = packed[j];
        unsigned va = *(const unsigned*)(hb + (long)(pa >> 3) * 64 + off);
        float ca = sc[(pa & 7) * 2 + sub];
        a0 = fmaf(ca, blo(va), a0);  a1 = fmaf(ca, bhi(va), a1);
    }
    a0 += __shfl_xor(a0, 16);  a1 += __shfl_xor(a1, 16);
    a0 += __shfl_xor(a0, 32);  a1 += __shfl_xor(a1, 32);
    if (lane < 16) {
        unsigned* p = (unsigned*)(h0 + (long)n * 32 + 2 * i2);
        unsigned cur = *p;
        *p = bpack(tanhf(blo(cur) + a0), tanhf(bhi(cur) + a1));
    }
}

// ---------------------------------------------------------------------------
// Layers 1/2 pull body (shared): unroll-8 (32 gathers in flight per wave).
__device__ __forceinline__
void pull_u_body(int n, int lane, const int* __restrict__ rowptr,
                 const unsigned* __restrict__ packed, const float* sc,
                 const u16* __restrict__ hsrc, u16* __restrict__ u)
{
    const int grp = lane >> 4;
    const int i2  = lane & 15;
    int beg = rowptr[n], end = rowptr[n + 1];
    float u00 = 0.f, u01 = 0.f, u10 = 0.f, u11 = 0.f;
    int j = beg + grp;
    for (; j + 28 < end; j += 32) {
        unsigned p[8], v[8];
        #pragma unroll
        for (int q = 0; q < 8; ++q) p[q] = packed[j + 4 * q];
        #pragma unroll
        for (int q = 0; q < 8; ++q)
            v[q] = *(const unsigned*)(hsrc + (long)(p[q] >> 3) * 32 + 2 * i2);
        #pragma unroll
        for (int q = 0; q < 8; ++q) {
            int r = (p[q] & 7) * 2;
            float lo = blo(v[q]), hi = bhi(v[q]);
            u00 = fmaf(sc[r], lo, u00);      u01 = fmaf(sc[r], hi, u01);
            u10 = fmaf(sc[r + 1], lo, u10);  u11 = fmaf(sc[r + 1], hi, u11);
        }
    }
    for (; j + 12 < end; j += 16) {
        unsigned pa = packed[j],     pb = packed[j + 4];
        unsigned pc = packed[j + 8], pd = packed[j + 12];
        unsigned va = *(const unsigned*)(hsrc + (long)(pa >> 3) * 32 + 2 * i2);
        unsigned vb = *(const unsigned*)(hsrc + (long)(pb >> 3) * 32 + 2 * i2);
        unsigned vc = *(const unsigned*)(hsrc + (long)(pc >> 3) * 32 + 2 * i2);
        unsigned vd = *(const unsigned*)(hsrc + (long)(pd >> 3) * 32 + 2 * i2);
        int ra = (pa & 7) * 2, rb = (pb & 7) * 2;
        int rc = (pc & 7) * 2, rd = (pd & 7) * 2;
        float alo = blo(va), ahi = bhi(va);
        float blo_ = blo(vb), bhi_ = bhi(vb);
        float clo = blo(vc), chi = bhi(vc);
        float dlo = blo(vd), dhi = bhi(vd);
        u00 = fmaf(sc[ra], alo, u00);      u01 = fmaf(sc[ra], ahi, u01);
        u10 = fmaf(sc[ra + 1], alo, u10);  u11 = fmaf(sc[ra + 1], ahi, u11);
        u00 = fmaf(sc[rb], blo_, u00);     u01 = fmaf(sc[rb], bhi_, u01);
        u10 = fmaf(sc[rb + 1], blo_, u10); u11 = fmaf(sc[rb + 1], bhi_, u11);
        u00 = fmaf(sc[rc], clo, u00);      u01 = fmaf(sc[rc], chi, u01);
        u10 = fmaf(sc[rc + 1], clo, u10);  u11 = fmaf(sc[rc + 1], chi, u11);
        u00 = fmaf(sc[rd], dlo, u00);      u01 = fmaf(sc[rd], dhi, u01);
        u10 = fmaf(sc[rd + 1], dlo, u10);  u11 = fmaf(sc[rd + 1], dhi, u11);
    }
    for (; j + 4 < end; j += 8) {
        unsigned pa = packed[j], pb = packed[j + 4];
        unsigned va = *(const unsigned*)(hsrc + (long)(pa >> 3) * 32 + 2 * i2);
        unsigned vb = *(const unsigned*)(hsrc + (long)(pb >> 3) * 32 + 2 * i2);
        int ra = (pa & 7) * 2, rb = (pb & 7) * 2;
        float alo = blo(va), ahi = bhi(va);
        float blo_ = blo(vb), bhi_ = bhi(vb);
        u00 = fmaf(sc[ra], alo, u00);      u01 = fmaf(sc[ra], ahi, u01);
        u10 = fmaf(sc[ra + 1], alo, u10);  u11 = fmaf(sc[ra + 1], ahi, u11);
        u00 = fmaf(sc[rb], blo_, u00);     u01 = fmaf(sc[rb], bhi_, u01);
        u10 = fmaf(sc[rb + 1], blo_, u10); u11 = fmaf(sc[rb + 1], bhi_, u11);
    }
    if (j < end) {
        unsigned pa = packed[j];
        unsigned va = *(const unsigned*)(hsrc + (long)(pa >> 3) * 32 + 2 * i2);
        int ra = (pa & 7) * 2;
        float alo = blo(va), ahi = bhi(va);
        u00 = fmaf(sc[ra], alo, u00);      u01 = fmaf(sc[ra], ahi, u01);
        u10 = fmaf(sc[ra + 1], alo, u10);  u11 = fmaf(sc[ra + 1], ahi, u11);
    }
    u00 += __shfl_xor(u00, 16);  u01 += __shfl_xor(u01, 16);
    u10 += __shfl_xor(u10, 16);  u11 += __shfl_xor(u11, 16);
    u00 += __shfl_xor(u00, 32);  u01 += __shfl_xor(u01, 32);
    u10 += __shfl_xor(u10, 32);  u11 += __shfl_xor(u11, 32);
    if (lane < 16) {
        unsigned* p0 = (unsigned*)(u + (long)n * 64 + 2 * i2);
        unsigned* p1 = (unsigned*)(u + (long)n * 64 + 32 + 2 * i2);
        *p0 = bpack(u00, u01);
        *p1 = bpack(u10, u11);
    }
}

// Layer-1 pull (all nodes).
__global__ __launch_bounds__(256)
void k_pull_u(const int* __restrict__ rowptr, const unsigned* __restrict__ packed,
              const float* __restrict__ comb, const u16* __restrict__ hsrc,
              u16* __restrict__ u, int nNodes)
{
    __shared__ float sc[16];
    if (threadIdx.x < 16) sc[threadIdx.x] = comb[threadIdx.x];
    __syncthreads();
    int n = blockIdx.x * 4 + (threadIdx.x >> 6);
    if (n >= nNodes) return;
    pull_u_body(n, threadIdx.x & 63, rowptr, packed, sc, hsrc, u);
}

// Layer-2 pull over REFERENCED nodes only.
__global__ __launch_bounds__(256)
void k_pull_uf(const int* __restrict__ rowptr, const unsigned* __restrict__ packed,
               const float* __restrict__ comb, const u16* __restrict__ hsrc,
               u16* __restrict__ u, const int* __restrict__ list,
               const int* __restrict__ cnt)
{
    __shared__ float sc[16];
    if (threadIdx.x < 16) sc[threadIdx.x] = comb[threadIdx.x];
    __syncthreads();
    const int count = *cnt;
    int idx = blockIdx.x * 4 + (threadIdx.x >> 6);
    if (idx >= count) return;
    pull_u_body(list[idx], threadIdx.x & 63, rowptr, packed, sc, hsrc, u);
}

// ---------------------------------------------------------------------------
// Post GEMM for layer 1 (all nodes — round-11 version).
__global__ __launch_bounds__(256, 2)
void k_post(const u16* __restrict__ u, const u16* __restrict__ hsrc,
            const float* __restrict__ V, const float* __restrict__ loopw,
            const float* __restrict__ bias, u16* __restrict__ hdst, int nNodes)
{
    __shared__ float CW[96 * 32];
    for (int idx = threadIdx.x; idx < 96 * 32; idx += 256) {
        int i = idx / 32, o = idx % 32;
        CW[idx] = (i < 64) ? V[i * 32 + o]
                           : loopw[(i - 64) * 32 + o];
    }
    __syncthreads();

    const int cg = threadIdx.x & 7;
    const int ng = threadIdx.x >> 3;
    const int c0 = cg * 4;
    const int base = blockIdx.x * 128 + ng * 4;
    if (base >= nNodes) return;

    long rows[4];
    #pragma unroll
    for (int j = 0; j < 4; ++j)
        rows[j] = (long)min(base + j, nNodes - 1);

    float acc[4][4] = {};
    #pragma unroll 2
    for (int i = 0; i < 96; i += 4) {
        f4 w0 = *(const f4*)&CW[(i + 0) * 32 + c0];
        f4 w1 = *(const f4*)&CW[(i + 1) * 32 + c0];
        f4 w2 = *(const f4*)&CW[(i + 2) * 32 + c0];
        f4 w3 = *(const f4*)&CW[(i + 3) * 32 + c0];
        #pragma unroll
        for (int j = 0; j < 4; ++j) {
            f4 hv;
            if (i < 64) hv = b4f(*(const us4*)(u + rows[j] * 64 + i));
            else        hv = b4f(*(const us4*)(hsrc + rows[j] * 32 + (i - 64)));
            #pragma unroll
            for (int q = 0; q < 4; ++q)
                acc[j][q] = fmaf(hv[3], w3[q],
                            fmaf(hv[2], w2[q],
                            fmaf(hv[1], w1[q],
                            fmaf(hv[0], w0[q], acc[j][q]))));
        }
    }

    f4 bv = *(const f4*)(bias + c0);
    #pragma unroll
    for (int j = 0; j < 4; ++j)
        if (base + j < nNodes) {
            us4 v = {f2b(tanhf(acc[j][0] + bv[0])), f2b(tanhf(acc[j][1] + bv[1])),
                     f2b(tanhf(acc[j][2] + bv[2])), f2b(tanhf(acc[j][3] + bv[3]))};
            *(us4*)(hdst + (long)(base + j) * 32 + c0) = v;
        }
}

// ---------------------------------------------------------------------------
// Post GEMM for layer 2 over REFERENCED nodes only.
__global__ __launch_bounds__(256, 2)
void k_postf(const u16* __restrict__ u, const u16* __restrict__ hsrc,
             const float* __restrict__ V, const float* __restrict__ loopw,
             const float* __restrict__ bias, u16* __restrict__ hdst,
             const int* __restrict__ list, const int* __restrict__ cnt)
{
    __shared__ float CW[96 * 32];
    for (int idx = threadIdx.x; idx < 96 * 32; idx += 256) {
        int i = idx / 32, o = idx % 32;
        CW[idx] = (i < 64) ? V[i * 32 + o]
                           : loopw[(i - 64) * 32 + o];
    }
    __syncthreads();

    const int count = *cnt;
    const int cg = threadIdx.x & 7;
    const int ng = threadIdx.x >> 3;
    const int c0 = cg * 4;
    const int base = blockIdx.x * 128 + ng * 4;
    if (base >= count) return;

    long rows[4];
    #pragma unroll
    for (int j = 0; j < 4; ++j)
        rows[j] = (long)list[min(base + j, count - 1)];

    float acc[4][4] = {};
    #pragma unroll 2
    for (int i = 0; i < 96; i += 4) {
        f4 w0 = *(const f4*)&CW[(i + 0) * 32 + c0];
        f4 w1 = *(const f4*)&CW[(i + 1) * 32 + c0];
        f4 w2 = *(const f4*)&CW[(i + 2) * 32 + c0];
        f4 w3 = *(const f4*)&CW[(i + 3) * 32 + c0];
        #pragma unroll
        for (int j = 0; j < 4; ++j) {
            f4 hv;
            if (i < 64) hv = b4f(*(const us4*)(u + rows[j] * 64 + i));
            else        hv = b4f(*(const us4*)(hsrc + rows[j] * 32 + (i - 64)));
            #pragma unroll
            for (int q = 0; q < 4; ++q)
                acc[j][q] = fmaf(hv[3], w3[q],
                            fmaf(hv[2], w2[q],
                            fmaf(hv[1], w1[q],
                            fmaf(hv[0], w0[q], acc[j][q]))));
        }
    }

    f4 bv = *(const f4*)(bias + c0);
    #pragma unroll
    for (int j = 0; j < 4; ++j)
        if (base + j < count) {
            us4 v = {f2b(tanhf(acc[j][0] + bv[0])), f2b(tanhf(acc[j][1] + bv[1])),
                     f2b(tanhf(acc[j][2] + bv[2])), f2b(tanhf(acc[j][3] + bv[3]))};
            *(us4*)(hdst + rows[j] * 32 + c0) = v;
        }
}

// ---------------------------------------------------------------------------
// Fused MLP heads + reparameterization over the COMPACTED node list only.
__global__ __launch_bounds__(256, 2)
void k_mlp(const u16* __restrict__ h0, const u16* __restrict__ h1,
           const u16* __restrict__ h2,
           const float* __restrict__ Wm1, const float* __restrict__ bm1,
           const float* __restrict__ Wm2, const float* __restrict__ bm2,
           const float* __restrict__ Ws1, const float* __restrict__ bs1,
           const float* __restrict__ Ws2, const float* __restrict__ bs2,
           const float* __restrict__ noise, float* __restrict__ z,
           const int* __restrict__ list, const int* __restrict__ cnt)
{
    const int count = *cnt;
    const int base = blockIdx.x * 64;
    if (base >= count) return;

    __shared__ float sW1[2][96 * 32];
    __shared__ float sW2[2][32 * 128];
    __shared__ float sb1[2][32];
    __shared__ float sb2[2][128];
    __shared__ float shid[2][64][32];

    for (int i = threadIdx.x; i < 96 * 32; i += 256) { sW1[0][i] = Wm1[i]; sW1[1][i] = Ws1[i]; }
    for (int i = threadIdx.x; i < 32 * 128; i += 256) { sW2[0][i] = Wm2[i]; sW2[1][i] = Ws2[i]; }
    if (threadIdx.x < 32)  { sb1[0][threadIdx.x] = bm1[threadIdx.x]; sb1[1][threadIdx.x] = bs1[threadIdx.x]; }
    if (threadIdx.x < 128) { sb2[0][threadIdx.x] = bm2[threadIdx.x]; sb2[1][threadIdx.x] = bs2[threadIdx.x]; }
    __syncthreads();

    // ---- phase A: hidden = relu(cs @ W1 + b1) ----
    {
        const int head = threadIdx.x >> 7;
        const int rem  = threadIdx.x & 127;
        const int ng   = rem >> 3;
        const int c0   = (rem & 7) * 4;
        const float* sW = sW1[head];
        long rows[4];
        #pragma unroll
        for (int j = 0; j < 4; ++j)
            rows[j] = (long)list[min(base + ng * 4 + j, count - 1)];

        float acc[4][4] = {};
        const u16* hs[3] = {h0, h1, h2};
        #pragma unroll
        for (int part = 0; part < 3; ++part) {
            const u16* hp = hs[part];
            #pragma unroll
            for (int kk = 0; kk < 32; kk += 4) {
                const int k = part * 32 + kk;
                f4 w0 = *(const f4*)&sW[(k + 0) * 32 + c0];
                f4 w1 = *(const f4*)&sW[(k + 1) * 32 + c0];
                f4 w2 = *(const f4*)&sW[(k + 2) * 32 + c0];
                f4 w3 = *(const f4*)&sW[(k + 3) * 32 + c0];
                #pragma unroll
                for (int j = 0; j < 4; ++j) {
                    f4 hv = b4f(*(const us4*)(hp + rows[j] * 32 + kk));
                    #pragma unroll
                    for (int q = 0; q < 4; ++q)
                        acc[j][q] = fmaf(hv[3], w3[q],
                                    fmaf(hv[2], w2[q],
                                    fmaf(hv[1], w1[q],
                                    fmaf(hv[0], w0[q], acc[j][q]))));
                }
            }
        }
        f4 bv = *(const f4*)&sb1[head][c0];
        #pragma unroll
        for (int j = 0; j < 4; ++j) {
            f4 v = {fmaxf(acc[j][0] + bv[0], 0.f), fmaxf(acc[j][1] + bv[1], 0.f),
                    fmaxf(acc[j][2] + bv[2], 0.f), fmaxf(acc[j][3] + bv[3], 0.f)};
            *(f4*)&shid[head][ng * 4 + j][c0] = v;
        }
    }
    __syncthreads();

    // ---- phase B: out = hid @ W2 + b2; z = mean + noise * exp(log_std) ----
    const int ng = threadIdx.x >> 5;
    const int c0 = (threadIdx.x & 31) * 4;
    #pragma unroll
    for (int pass = 0; pass < 2; ++pass) {
        const int nb = pass * 32 + ng * 4;
        float am[4][4] = {}, as_[4][4] = {};
        #pragma unroll 4
        for (int k = 0; k < 32; k += 4) {
            f4 wm0 = *(const f4*)&sW2[0][(k + 0) * 128 + c0];
            f4 wm1 = *(const f4*)&sW2[0][(k + 1) * 128 + c0];
            f4 wm2 = *(const f4*)&sW2[0][(k + 2) * 128 + c0];
            f4 wm3 = *(const f4*)&sW2[0][(k + 3) * 128 + c0];
            f4 ws0 = *(const f4*)&sW2[1][(k + 0) * 128 + c0];
            f4 ws1 = *(const f4*)&sW2[1][(k + 1) * 128 + c0];
            f4 ws2 = *(const f4*)&sW2[1][(k + 2) * 128 + c0];
            f4 ws3 = *(const f4*)&sW2[1][(k + 3) * 128 + c0];
            #pragma unroll
            for (int j = 0; j < 4; ++j) {
                f4 hm = *(const f4*)&shid[0][nb + j][k];
                f4 hv = *(const f4*)&shid[1][nb + j][k];
                #pragma unroll
                for (int q = 0; q < 4; ++q) {
                    am[j][q]  = fmaf(hm[3], wm3[q],
                                fmaf(hm[2], wm2[q],
                                fmaf(hm[1], wm1[q],
                                fmaf(hm[0], wm0[q], am[j][q]))));
                    as_[j][q] = fmaf(hv[3], ws3[q],
                                fmaf(hv[2], ws2[q],
                                fmaf(hv[1], ws1[q],
                                fmaf(hv[0], ws0[q], as_[j][q]))));
                }
            }
        }
        f4 b2m = *(const f4*)&sb2[0][c0];
        f4 b2s = *(const f4*)&sb2[1][c0];
        #pragma unroll
        for (int j = 0; j < 4; ++j) {
            const int idx = base + nb + j;
            if (idx < count) {
                const long n = (long)list[idx];
                f4 nz = *(const f4*)(noise + n * 128 + c0);
                f4 v;
                #pragma unroll
                for (int q = 0; q < 4; ++q)
                    v[q] = fmaf(nz[q], expf(as_[j][q] + b2s[q]), am[j][q] + b2m[q]);
                *(f4*)(z + n * 128 + c0) = v;
            }
        }
    }
}

// ---------------------------------------------------------------------------
__global__ __launch_bounds__(256)
void k_pairs(const float* __restrict__ z, const int* __restrict__ ui,
             const int* __restrict__ ii, float* __restrict__ out, int U, int T)
{
    int w = (blockIdx.x * 256 + threadIdx.x) >> 6;
    int lane = threadIdx.x & 63;
    if (w >= U) return;
    int a = ui[w], b = ii[w];
    float a0 = z[(long)a * 128 + lane], a1 = z[(long)a * 128 + 64 + lane];
    float b0 = z[(long)b * 128 + lane], b1 = z[(long)b * 128 + 64 + lane];
    float* res = out + U + T;
    res[(long)w * 128 + lane] = a0;
    res[(long)w * 128 + 64 + lane] = a1;
    res[(long)(U + w) * 128 + lane] = b0;
    res[(long)(U + w) * 128 + 64 + lane] = b1;
    float d = fmaf(a0, b0, a1 * b1);
    #pragma unroll
    for (int off = 32; off; off >>= 1) d += __shfl_xor(d, off);
    if (lane == 0) out[w] = d;
}

__global__ __launch_bounds__(256)
void k_preds(const float* __restrict__ z, const int* __restrict__ ts,
             const int* __restrict__ td, float* __restrict__ out, int U, int T)
{
    int w = (blockIdx.x * 256 + threadIdx.x) >> 6;
    int lane = threadIdx.x & 63;
    if (w >= T) return;
    int a = ts[w], b = td[w];
    float a0 = z[(long)a * 128 + lane], a1 = z[(long)a * 128 + 64 + lane];
    float b0 = z[(long)b * 128 + lane], b1 = z[(long)b * 128 + 64 + lane];
    float d = fmaf(a0, b0, a1 * b1);
    #pragma unroll
    for (int off = 32; off; off >>= 1) d += __shfl_xor(d, off);
    if (lane == 0) out[U + w] = d;
}

// ---------------------------------------------------------------------------
extern "C" void kernel_launch(void* const* d_in, const int* in_sizes, int n_in,
                              void* d_out, int out_size, void* d_ws, size_t ws_size,
                              hipStream_t stream)
{
    const float* x     = (const float*)d_in[0];
    const int*   src   = (const int*)d_in[1];
    const int*   dst   = (const int*)d_in[2];
    const int*   et    = (const int*)d_in[3];
    const float* noise = (const float*)d_in[4];
    const int*   ui    = (const int*)d_in[5];
    const int*   ii    = (const int*)d_in[6];
    const int*   tes   = (const int*)d_in[7];
    const int*   ted   = (const int*)d_in[8];
    const float* V0    = (const float*)d_in[9];
    const float* comb0 = (const float*)d_in[10];
    const float* loop0 = (const float*)d_in[11];
    const float* b0    = (const float*)d_in[12];
    const float* V1    = (const float*)d_in[13];
    const float* comb1 = (const float*)d_in[14];
    const float* loop1 = (const float*)d_in[15];
    const float* b1    = (const float*)d_in[16];
    const float* V2    = (const float*)d_in[17];
    const float* comb2 = (const float*)d_in[18];
    const float* loop2 = (const float*)d_in[19];
    const float* b2    = (const float*)d_in[20];
    const float* Wm1   = (const float*)d_in[21];
    const float* bm1   = (const float*)d_in[22];
    const float* Wm2   = (const float*)d_in[23];
    const float* bm2   = (const float*)d_in[24];
    const float* Ws1   = (const float*)d_in[25];
    const float* bs1   = (const float*)d_in[26];
    const float* Ws2   = (const float*)d_in[27];
    const float* bs2   = (const float*)d_in[28];

    const int N = in_sizes[0] / 128;   // 200000
    const int E = in_sizes[1];         // 3200000
    const int U = in_sizes[5];
    const int T = in_sizes[7];
    const int NB = (N + 255) / 256;    // 782 buckets
    const int chunk = (E + NBLK - 1) / NBLK;

    float* out = (float*)d_out;

    // Workspace layout (bytes):
    //  hb  bf16 [N][64] | h0/h1/h2 bf16 [N][32] | u bf16 [N][64]
    //  z f32 [N][128]  (CSR int scratch aliases z; dead by k_mlp)
    //  flags char[N] | list int[N] | cnt int
    char* W = (char*)d_ws;
    u16*   hb = (u16*)W;
    u16*   h0 = (u16*)(W + (size_t)N * 64 * 2);
    u16*   h1 = h0 + (size_t)N * 32;
    u16*   h2 = h1 + (size_t)N * 32;
    u16*   u  = (u16*)(W + (size_t)N * 64 * 2 + (size_t)N * 32 * 2 * 3);
    float* z  = (float*)(u + (size_t)N * 64);
    unsigned char* flags = (unsigned char*)(z + (size_t)N * 128);
    int*   list = (int*)(flags + (size_t)N);
    int*   cnt  = list + N;

    int*      rowptr = (int*)z;
    unsigned* packed = (unsigned*)(rowptr + N + 1);
    unsigned* bpk    = packed + E;
    int*      hist   = (int*)(bpk + E);
    int*      basep  = hist + NBLK * MAXB;
    int*      colsum = basep + NBLK * MAXB;
    int*      bb     = colsum + NB;

    const int hbBlocks   = (N + 63) / 64;
    const int pullBlocks = (N + 3) / 4;
    const int postBlocks = (N + 127) / 128;
    const int mlpBlocks  = (N + 63) / 64;

    // ---- referenced-node flags + compaction ----
    k_zerof<<<(N / 4 + 255) / 256, 256, 0, stream>>>((int*)flags, N / 4, cnt);
    k_flags<<<(2 * U + 2 * T + 255) / 256, 256, 0, stream>>>(ui, ii, tes, ted, U, T, flags);
    k_compact<<<NB, 256, 0, stream>>>(flags, list, cnt, N);

    // ---- contention-free bucketed CSR build (by dst) ----
    k_bhist2<<<NBLK, 256, 0, stream>>>(dst, hist, E, NB, chunk);
    k_colscan<<<NB, 256, 0, stream>>>(hist, basep, colsum, NB);
    k_bscan2<<<1, 1024, 0, stream>>>(colsum, bb, rowptr, NB, N, E);
    k_bscatter2<<<NBLK, 256, 0, stream>>>(src, dst, et, basep, bb, bpk, E, NB, chunk);
    k_bucket<<<NB, 256, 0, stream>>>(bpk, bb, rowptr, packed, N);

    // ---- layer 0 (MFMA GEMM + pull) ----
    k_hb<<<hbBlocks, 256, 0, stream>>>(x, V0, loop0, b0, hb, h0, N);
    k_pull0<<<pullBlocks, 256, 0, stream>>>(rowptr, packed, comb0, hb, h0, N);

    // ---- layer 1 (all nodes) ----
    k_pull_u<<<pullBlocks, 256, 0, stream>>>(rowptr, packed, comb1, h0, u, N);
    k_post<<<postBlocks, 256, 0, stream>>>(u, h0, V1, loop1, b1, h1, N);

    // ---- layer 2 (referenced nodes only) ----
    k_pull_uf<<<pullBlocks, 256, 0, stream>>>(rowptr, packed, comb2, h1, u, list, cnt);
    k_postf<<<postBlocks, 256, 0, stream>>>(u, h1, V2, loop2, b2, h2, list, cnt);

    // ---- heads + reparameterization (compacted) ----
    k_mlp<<<mlpBlocks, 256, 0, stream>>>(h0, h1, h2, Wm1, bm1, Wm2, bm2,
                                         Ws1, bs1, Ws2, bs2, noise, z, list, cnt);
    // ---- outputs ----
    k_pairs<<<(U * 64 + 255) / 256, 256, 0, stream>>>(z, ui, ii, out, U, T);
    k_preds<<<(T * 64 + 255) / 256, 256, 0, stream>>>(z, tes, ted, out, U, T);
}